// Round 4
// baseline (687.659 us; speedup 1.0000x reference)
//
#include <hip/hip_runtime.h>

// ---------------------------------------------------------------------------
// VQ-VAE forward — split-fp16 MFMA everywhere.
// x = h + l*2^-11 (l prescaled by 2^11), w likewise; acc1 = h*wh,
// acc2 = h*wl + l*wh; result = acc1 + acc2/2048.  (fp32-accurate)
// Verified MFMA mapping: A[m=lane&15][k=quad*8+j] (8 consecutive k),
// B rows [n][kk] (8 consecutive kk at col n=lane&15), D col=lane&15,
// row=quad*4+reg.  kk = ci*4 + tap, tap padded to 4 with zero weights.
// R3 lesson: NEVER index register arrays with runtime values.
// R6 lesson: direct-from-global A/B fragment gathers are TA/L1 SEGMENT-bound
// (stride-2 gathers ~10 seg/instr, B int4 at 6KB stride = 16 seg/instr;
// ~24M segments ≈ 150us). Adding waves (occupancy 19->38%) gave only 9%.
// R7 change: conv1 back to LDS staging, structured right:
//  - chunk = 16ch x 132 pos, staged with guarded float4 (coalesced),
//  - h/l SPLIT ONCE during staging (f16 planes, 17KB LDS, no splitf in
//    compute), ONE barrier per chunk (T14: load-early/write-late dbuf),
//  - LDS window reads are stride-1 dwords per lane (2-way max = free),
//  - split-K z=4 and PSUM consumer unchanged from R6 (verified).
// ---------------------------------------------------------------------------

typedef _Float16 half8 __attribute__((ext_vector_type(8)));
typedef float f32x4 __attribute__((ext_vector_type(4)));
union H8u { half8 h; int4 i; };
union P4u { _Float16 e[4]; int2 u; };

__device__ __forceinline__ void splitf(float v, _Float16& h, _Float16& l) {
  h = (_Float16)v; l = (_Float16)((v - (float)h) * 2048.0f);
}
#define INV2048 (1.0f / 2048.0f)

// ---- prepped-weight layout offsets (f16 elements) ----
#define OFF_C1   0        // conv1  [32][3072]
#define OFF_C2   98304    // conv2  [64][128]
#define OFF_C3   106496   // conv3  [64][256]
#define OFF_ER0A 122880   // enc r0 conv3 [32][256]
#define OFF_ER0B 131072   // enc r0 1x1   [64][32]
#define OFF_ER1A 133120
#define OFF_ER1B 141312
#define OFF_PQ   143360   // prevq [64][64]
#define OFF_DW1  147456   // dec conv1 [64][256]
#define OFF_DR0A 163840
#define OFF_DR0B 172032
#define OFF_DR1A 174080
#define OFF_DR1B 182272
#define OFF_T1   184320   // convT1 [64=par*32+co][256]
#define OFF_T2   200704   // convT2 [128=par*64+co][128]
#define WTOT     217088

struct WPtrs {
  const float *c1, *c2, *c3, *er0a, *er0b, *er1a, *er1b, *pq,
              *dw1, *dr0a, *dr0b, *dr1a, *dr1b, *t1, *t2;
};

__device__ __forceinline__ int tpose_kt(int par, int tap) {
  if (par == 0) { if (tap == 0) return 3; if (tap == 1) return 1; }
  else          { if (tap == 1) return 2; if (tap == 2) return 0; }
  return -1;
}

__global__ __launch_bounds__(256) void prep_k(WPtrs P, _Float16* __restrict__ WH,
                                              _Float16* __restrict__ WL) {
  int s = blockIdx.x * 256 + threadIdx.x;
  if (s >= WTOT) return;
  float v = 0.f;
  if (s < OFF_C2) {
    int t = s, co = t / 3072, kk = t % 3072;
    v = P.c1[(co * 768 + (kk >> 2)) * 4 + (kk & 3)];
  } else if (s < OFF_C3) {
    int t = s - OFF_C2, co = t >> 7, kk = t & 127;
    v = P.c2[(co * 32 + (kk >> 2)) * 4 + (kk & 3)];
  } else if (s < OFF_ER0A) {
    int t = s - OFF_C3, co = t >> 8, kk = t & 255, tap = kk & 3;
    if (tap < 3) v = P.c3[(co * 64 + (kk >> 2)) * 3 + tap];
  } else if (s < OFF_ER0B) {
    int t = s - OFF_ER0A, co = t >> 8, kk = t & 255, tap = kk & 3;
    if (tap < 3) v = P.er0a[(co * 64 + (kk >> 2)) * 3 + tap];
  } else if (s < OFF_ER1A) {
    int t = s - OFF_ER0B; v = P.er0b[t];
  } else if (s < OFF_ER1B) {
    int t = s - OFF_ER1A, co = t >> 8, kk = t & 255, tap = kk & 3;
    if (tap < 3) v = P.er1a[(co * 64 + (kk >> 2)) * 3 + tap];
  } else if (s < OFF_PQ) {
    int t = s - OFF_ER1B; v = P.er1b[t];
  } else if (s < OFF_DW1) {
    int t = s - OFF_PQ; v = P.pq[t];
  } else if (s < OFF_DR0A) {
    int t = s - OFF_DW1, co = t >> 8, kk = t & 255, tap = kk & 3;
    if (tap < 3) v = P.dw1[(co * 64 + (kk >> 2)) * 3 + tap];
  } else if (s < OFF_DR0B) {
    int t = s - OFF_DR0A, co = t >> 8, kk = t & 255, tap = kk & 3;
    if (tap < 3) v = P.dr0a[(co * 64 + (kk >> 2)) * 3 + tap];
  } else if (s < OFF_DR1A) {
    int t = s - OFF_DR0B; v = P.dr0b[t];
  } else if (s < OFF_DR1B) {
    int t = s - OFF_DR1A, co = t >> 8, kk = t & 255, tap = kk & 3;
    if (tap < 3) v = P.dr1a[(co * 64 + (kk >> 2)) * 3 + tap];
  } else if (s < OFF_T1) {
    int t = s - OFF_DR1B; v = P.dr1b[t];
  } else if (s < OFF_T2) {
    int t = s - OFF_T1, nn = t >> 8, kk = t & 255;
    int par = nn >> 5, co = nn & 31, ci = kk >> 2;
    int kt = tpose_kt(par, kk & 3);
    if (kt >= 0) v = P.t1[(ci * 32 + co) * 4 + kt];
  } else {
    int t = s - OFF_T2, nn = t >> 7, kk = t & 127;
    int par = nn >> 6, co = nn & 63, ci = kk >> 2;
    int kt = tpose_kt(par, kk & 3);
    if (kt >= 0) v = P.t2[(ci * 64 + co) * 4 + kt];
  }
  _Float16 h, l; splitf(v, h, l);
  WH[s] = h; WL[s] = l;
}

// --------------------------- conv1 (768->32, k4 s2) -------------------------
// LDS-staged, single-barrier double-buffered pipeline, SPLIT-K.
// Block = 4 waves, M-tile 64 (wave w owns rows r = w*16+lm). Chunk = 16
// channels x 132 staged positions (local q = global p - (2*m0-1), q in
// [0,131]); window for row r is q = 2r..2r+3 -> 2 dwords at dword index
// ci*68 + r (lane stride 1 => conflict-free). h/l split happens during
// staging. blockIdx.z = kpart; raw fp32 partials -> Pout planes (PSUM in
// conv2 sums + bias + relu).
__global__ __launch_bounds__(256, 6) void conv1_k(
    const float* __restrict__ x, const _Float16* __restrict__ WH,
    const _Float16* __restrict__ WL, float* __restrict__ Pout, int cpp) {
  __shared__ _Float16 Hs[2][16 * 136];
  __shared__ _Float16 Ls[2][16 * 136];
  const int tid = threadIdx.x;
  const int w = tid >> 6, lane = tid & 63, lm = lane & 15, quad = lane >> 4;
  const int m0 = blockIdx.x * 64, n = blockIdx.y, kpart = blockIdx.z;
  const int r = w * 16 + lm;                  // wave-local output row 0..63
  const int pb = 2 * m0 - 1;                  // global pos of local q=0
  const float* xn = x + (size_t)n * 768 * 4096;
  // staging slots: 528 = 16 rows x 33 float4; slot2 only for tid<16
  const int r0s = tid / 33, c0s = tid % 33;
  const int r1s = (256 + tid) / 33, c1s = (256 + tid) % 33;
  const int r2s = (512 + tid) / 33, c2s = (512 + tid) % 33;
  // B pointers (prepped layout [32][3072])
  const _Float16* bh0 = WH + (size_t)lm * 3072 + quad * 8;
  const _Float16* bl0 = WL + (size_t)lm * 3072 + quad * 8;
  const _Float16* bh1 = bh0 + 16 * 3072;
  const _Float16* bl1 = bl0 + 16 * 3072;

  f32x4 acc1[2], acc2[2];
#pragma unroll
  for (int j = 0; j < 2; ++j)
#pragma unroll
    for (int rr = 0; rr < 4; ++rr) { acc1[j][rr] = 0.f; acc2[j][rr] = 0.f; }

  const int cb0 = kpart * cpp;
  float4 sv0, sv1, sv2;

#define C1_LD1(SV, RS, CS) { \
    int p0 = pb + 4 * (CS); \
    const float* rp = xn + (size_t)(chb + (RS)) * 4096; \
    if (p0 >= 0 && p0 + 3 < 4096) SV = *(const float4*)(rp + p0); \
    else { \
      SV.x = (p0   >= 0 && p0   < 4096) ? rp[p0]   : 0.f; \
      SV.y = (p0+1 >= 0 && p0+1 < 4096) ? rp[p0+1] : 0.f; \
      SV.z = (p0+2 >= 0 && p0+2 < 4096) ? rp[p0+2] : 0.f; \
      SV.w = (p0+3 >= 0 && p0+3 < 4096) ? rp[p0+3] : 0.f; } }

#define C1_LOAD(cc) { \
    int chb = (cb0 + (cc)) * 16; \
    C1_LD1(sv0, r0s, c0s) \
    C1_LD1(sv1, r1s, c1s) \
    if (tid < 16) C1_LD1(sv2, r2s, c2s) }

#define C1_WR1(SV, RS, CS, B) { \
    P4u ph, pl; \
    splitf(SV.x, ph.e[0], pl.e[0]); splitf(SV.y, ph.e[1], pl.e[1]); \
    splitf(SV.z, ph.e[2], pl.e[2]); splitf(SV.w, ph.e[3], pl.e[3]); \
    *(int2*)(&Hs[B][(RS) * 136 + 4 * (CS)]) = ph.u; \
    *(int2*)(&Ls[B][(RS) * 136 + 4 * (CS)]) = pl.u; }

#define C1_WRITE(B) { \
    C1_WR1(sv0, r0s, c0s, B) \
    C1_WR1(sv1, r1s, c1s, B) \
    if (tid < 16) C1_WR1(sv2, r2s, c2s, B) }

#define C1_COMP(cc, B) { \
    const uint* Hdw = (const uint*)(&Hs[B][0]); \
    const uint* Ldw = (const uint*)(&Ls[B][0]); \
    const int kkb = ((cb0 + (cc)) * 64); \
    _Pragma("unroll") \
    for (int ks = 0; ks < 2; ++ks) { \
      const int ci0 = ks * 8 + quad * 2; \
      const int bse = ci0 * 68 + r; \
      H8u ah, al; \
      ah.i.x = Hdw[bse];      ah.i.y = Hdw[bse + 1]; \
      ah.i.z = Hdw[bse + 68]; ah.i.w = Hdw[bse + 69]; \
      al.i.x = Ldw[bse];      al.i.y = Ldw[bse + 1]; \
      al.i.z = Ldw[bse + 68]; al.i.w = Ldw[bse + 69]; \
      H8u b0h, b0l, b1h, b1l; \
      b0h.i = *(const int4*)(bh0 + kkb + ks * 32); \
      b0l.i = *(const int4*)(bl0 + kkb + ks * 32); \
      b1h.i = *(const int4*)(bh1 + kkb + ks * 32); \
      b1l.i = *(const int4*)(bl1 + kkb + ks * 32); \
      acc1[0] = __builtin_amdgcn_mfma_f32_16x16x32_f16(ah.h, b0h.h, acc1[0], 0,0,0); \
      acc2[0] = __builtin_amdgcn_mfma_f32_16x16x32_f16(ah.h, b0l.h, acc2[0], 0,0,0); \
      acc2[0] = __builtin_amdgcn_mfma_f32_16x16x32_f16(al.h, b0h.h, acc2[0], 0,0,0); \
      acc1[1] = __builtin_amdgcn_mfma_f32_16x16x32_f16(ah.h, b1h.h, acc1[1], 0,0,0); \
      acc2[1] = __builtin_amdgcn_mfma_f32_16x16x32_f16(ah.h, b1l.h, acc2[1], 0,0,0); \
      acc2[1] = __builtin_amdgcn_mfma_f32_16x16x32_f16(al.h, b1h.h, acc2[1], 0,0,0); \
    } }

  // prologue: stage chunk 0 into buffer 0
  C1_LOAD(0);
  C1_WRITE(0);
  __syncthreads();
#pragma unroll 1
  for (int cc = 0; cc < cpp; ++cc) {
    const int cur = cc & 1;
    if (cc + 1 < cpp) C1_LOAD(cc + 1);   // issue next-chunk loads early
    C1_COMP(cc, cur);                    // compute current from LDS
    if (cc + 1 < cpp) C1_WRITE(cur ^ 1); // write next buffer late
    __syncthreads();                     // one barrier per chunk
  }

  // epilogue: raw partial (bias/relu deferred to conv2's staging)
#pragma unroll
  for (int j = 0; j < 2; ++j) {
    int col = j * 16 + lm;
    float4 o;
    o.x = acc1[j][0] + acc2[j][0] * INV2048;
    o.y = acc1[j][1] + acc2[j][1] * INV2048;
    o.z = acc1[j][2] + acc2[j][2] * INV2048;
    o.w = acc1[j][3] + acc2[j][3] * INV2048;
    *(float4*)(Pout + (size_t)kpart * (16 * 32 * 2048)
               + ((size_t)n * 32 + col) * 2048 + m0 + w * 16 + quad * 4) = o;
  }
#undef C1_LD1
#undef C1_LOAD
#undef C1_WR1
#undef C1_WRITE
#undef C1_COMP
}

// ------------------- generic one-shot MFMA conv (M-tile 32) -----------------
// PSUM: input is `nparts` raw partial planes (stride pplane floats); staging
// sums them, adds inbias[row], applies relu — in-range elements only.
template<int CI, int KP, int NT, int STRIDE,
         bool RELU_IN, bool RELU_OUT, bool BIAS, bool TPOSE, bool RESBLK,
         bool PSUM = false>
__global__ __launch_bounds__(256) void gconv(
    const float* __restrict__ in, const _Float16* __restrict__ WH,
    const _Float16* __restrict__ WL, const float* __restrict__ bias,
    const _Float16* __restrict__ W2H, const _Float16* __restrict__ W2L,
    float* __restrict__ out, int Lin, int Lout,
    const float* __restrict__ inbias, int nparts, int pplane) {
  constexpr int CP = 32 * STRIDE + 4;
  constexpr int CP4 = CP / 4;
  constexpr int AP = KP + 8;
  constexpr int KS = KP / 32;
  constexpr int NTW = (NT == 2) ? 1 : NT / 2;
  __shared__ float xs[CI * CP];
  __shared__ _Float16 Ah[32 * AP];
  __shared__ _Float16 Al[32 * AP];
  __shared__ _Float16 A2h[RESBLK ? 32 * 40 : 1];
  __shared__ _Float16 A2l[RESBLK ? 32 * 40 : 1];
  const int tid = threadIdx.x;
  const int w = tid >> 6, lane = tid & 63, lm = lane & 15, quad = lane >> 4;
  const int mt = w >> 1, ntb = (w & 1) * NTW;
  const int m0 = blockIdx.x * 32, n = blockIdx.y;
  const int base = m0 * STRIDE - 1;
  const float* inN = in + (size_t)n * CI * Lin;
  constexpr int SLOTS = CI * CP4;
#pragma unroll
  for (int it = 0; it < (SLOTS + 255) / 256; ++it) {
    int idx = it * 256 + tid;
    if (idx < SLOTS) {
      int row = idx / CP4, c4 = idx % CP4;
      int p0 = base + c4 * 4;
      const float* rp = inN + (size_t)row * Lin;
      float4 v;
      if (PSUM) {
        v.x = 0.f; v.y = 0.f; v.z = 0.f; v.w = 0.f;
        bool i0 = (p0   >= 0 && p0   < Lin);
        bool i1 = (p0+1 >= 0 && p0+1 < Lin);
        bool i2 = (p0+2 >= 0 && p0+2 < Lin);
        bool i3 = (p0+3 >= 0 && p0+3 < Lin);
        bool full = (p0 >= 0 && p0 + 3 < Lin);
        for (int p = 0; p < nparts; ++p) {
          const float* rpp = rp + (size_t)p * pplane;
          if (full) {
            float4 t = *(const float4*)(rpp + p0);
            v.x += t.x; v.y += t.y; v.z += t.z; v.w += t.w;
          } else {
            if (i0) v.x += rpp[p0];
            if (i1) v.y += rpp[p0+1];
            if (i2) v.z += rpp[p0+2];
            if (i3) v.w += rpp[p0+3];
          }
        }
        float bv = inbias[row];
        v.x = i0 ? fmaxf(v.x + bv, 0.f) : 0.f;
        v.y = i1 ? fmaxf(v.y + bv, 0.f) : 0.f;
        v.z = i2 ? fmaxf(v.z + bv, 0.f) : 0.f;
        v.w = i3 ? fmaxf(v.w + bv, 0.f) : 0.f;
      } else {
        if (p0 >= 0 && p0 + 3 < Lin) v = *(const float4*)(rp + p0);
        else {
          v.x = (p0   >= 0 && p0   < Lin) ? rp[p0]   : 0.f;
          v.y = (p0+1 >= 0 && p0+1 < Lin) ? rp[p0+1] : 0.f;
          v.z = (p0+2 >= 0 && p0+2 < Lin) ? rp[p0+2] : 0.f;
          v.w = (p0+3 >= 0 && p0+3 < Lin) ? rp[p0+3] : 0.f;
        }
      }
      *(float4*)(&xs[row * CP + c4 * 4]) = v;
    }
  }
  __syncthreads();
#pragma unroll
  for (int it = 0; it < (32 * CI) / 256; ++it) {
    int slot = it * 256 + tid;
    int ci = slot & (CI - 1), m = slot / CI;
    const float* xr = &xs[ci * CP + STRIDE * m];
    float a0 = xr[0], a1 = xr[1], a2 = xr[2], a3 = xr[3];
    if (RELU_IN) { a0 = fmaxf(a0,0.f); a1 = fmaxf(a1,0.f);
                   a2 = fmaxf(a2,0.f); a3 = fmaxf(a3,0.f); }
    P4u ph, pl;
    splitf(a0, ph.e[0], pl.e[0]); splitf(a1, ph.e[1], pl.e[1]);
    splitf(a2, ph.e[2], pl.e[2]); splitf(a3, ph.e[3], pl.e[3]);
    *(int2*)(&Ah[m * AP + ci * 4]) = ph.u;
    *(int2*)(&Al[m * AP + ci * 4]) = pl.u;
  }
  __syncthreads();
  f32x4 acc1[NTW], acc2[NTW];
#pragma unroll
  for (int j = 0; j < NTW; ++j)
#pragma unroll
    for (int r = 0; r < 4; ++r) { acc1[j][r] = 0.f; acc2[j][r] = 0.f; }
  H8u bh[2][NTW], bl[2][NTW];
#pragma unroll
  for (int j = 0; j < NTW; ++j) {
    int col = (ntb + j) * 16 + lm;
    bh[0][j].i = *(const int4*)(WH + (size_t)col * KP + quad * 8);
    bl[0][j].i = *(const int4*)(WL + (size_t)col * KP + quad * 8);
  }
#pragma unroll
  for (int ks = 0; ks < KS; ++ks) {
    int cur = ks & 1;                      // static after full unroll
    if (ks + 1 < KS) {
#pragma unroll
      for (int j = 0; j < NTW; ++j) {
        int col = (ntb + j) * 16 + lm;
        bh[cur ^ 1][j].i = *(const int4*)(WH + (size_t)col * KP + (ks+1) * 32 + quad * 8);
        bl[cur ^ 1][j].i = *(const int4*)(WL + (size_t)col * KP + (ks+1) * 32 + quad * 8);
      }
    }
    H8u ah, al;
    ah.i = *(const int4*)(&Ah[(mt * 16 + lm) * AP + ks * 32 + quad * 8]);
    al.i = *(const int4*)(&Al[(mt * 16 + lm) * AP + ks * 32 + quad * 8]);
#pragma unroll
    for (int j = 0; j < NTW; ++j) {
      acc1[j] = __builtin_amdgcn_mfma_f32_16x16x32_f16(ah.h, bh[cur][j].h, acc1[j], 0,0,0);
      acc2[j] = __builtin_amdgcn_mfma_f32_16x16x32_f16(ah.h, bl[cur][j].h, acc2[j], 0,0,0);
      acc2[j] = __builtin_amdgcn_mfma_f32_16x16x32_f16(al.h, bh[cur][j].h, acc2[j], 0,0,0);
    }
  }
  if (RESBLK) {
    int co2 = (w & 1) * 16 + lm;
#pragma unroll
    for (int r = 0; r < 4; ++r) {
      float hv = fmaxf(acc1[0][r] + acc2[0][r] * INV2048, 0.f);
      _Float16 hh, hl; splitf(hv, hh, hl);
      int m = mt * 16 + quad * 4 + r;
      A2h[m * 40 + co2] = hh; A2l[m * 40 + co2] = hl;
    }
    __syncthreads();
    f32x4 c1[2], c2[2];
#pragma unroll
    for (int j = 0; j < 2; ++j)
#pragma unroll
      for (int r = 0; r < 4; ++r) { c1[j][r] = 0.f; c2[j][r] = 0.f; }
    H8u a2h, a2l;
    a2h.i = *(const int4*)(&A2h[(mt * 16 + lm) * 40 + quad * 8]);
    a2l.i = *(const int4*)(&A2l[(mt * 16 + lm) * 40 + quad * 8]);
    int ntb2 = (w & 1) * 2;
#pragma unroll
    for (int j = 0; j < 2; ++j) {
      int col = (ntb2 + j) * 16 + lm;
      H8u wbh, wbl;
      wbh.i = *(const int4*)(W2H + col * 32 + quad * 8);
      wbl.i = *(const int4*)(W2L + col * 32 + quad * 8);
      c1[j] = __builtin_amdgcn_mfma_f32_16x16x32_f16(a2h.h, wbh.h, c1[j], 0,0,0);
      c2[j] = __builtin_amdgcn_mfma_f32_16x16x32_f16(a2h.h, wbl.h, c2[j], 0,0,0);
      c2[j] = __builtin_amdgcn_mfma_f32_16x16x32_f16(a2l.h, wbh.h, c2[j], 0,0,0);
    }
#pragma unroll
    for (int j = 0; j < 2; ++j) {
      int col = (ntb2 + j) * 16 + lm;
      float4 o;
#pragma unroll
      for (int r = 0; r < 4; ++r) {
        int m = mt * 16 + quad * 4 + r;
        float res = xs[col * CP + m + 1];
        ((float*)&o)[r] = res + c1[j][r] + c2[j][r] * INV2048;
      }
      *(float4*)(out + ((size_t)n * 64 + col) * Lout + m0 + mt * 16 + quad * 4) = o;
    }
  } else {
    constexpr int CO = TPOSE ? NT * 8 : NT * 16;
#pragma unroll
    for (int j = 0; j < NTW; ++j) {
      int col = (ntb + j) * 16 + lm;
      int par = TPOSE ? (col / CO) : 0;
      int co  = TPOSE ? (col % CO) : col;
      float bv = BIAS ? bias[co] : 0.f;
      float vr[4];
#pragma unroll
      for (int r = 0; r < 4; ++r) {
        float v = acc1[j][r] + acc2[j][r] * INV2048 + bv;
        vr[r] = RELU_OUT ? fmaxf(v, 0.f) : v;
      }
      if (TPOSE) {
#pragma unroll
        for (int r = 0; r < 4; ++r) {
          int m = m0 + mt * 16 + quad * 4 + r;
          out[((size_t)n * CO + co) * Lout + 2 * m + par] = vr[r];
        }
      } else {
        float4 o; o.x = vr[0]; o.y = vr[1]; o.z = vr[2]; o.w = vr[3];
        *(float4*)(out + ((size_t)n * CO + co) * Lout + m0 + mt * 16 + quad * 4) = o;
      }
    }
  }
}

// ------------------------------ codebook norms ------------------------------
__global__ void enorm_k(const float* __restrict__ emb, float* __restrict__ en) {
  int e = blockIdx.x * blockDim.x + threadIdx.x;
  if (e >= 512) return;
  float s = 0.f;
  const float* r = emb + (size_t)e * 64;
  for (int c = 0; c < 64; ++c) s = fmaf(r[c], r[c], s);
  en[e] = s;
}

// ------------------ fused prevq (1x1, relu-in) + VQ -------------------------
__global__ __launch_bounds__(256) void vq_fused(
    const float* __restrict__ sIn, const _Float16* __restrict__ PQH,
    const _Float16* __restrict__ PQL, const float* __restrict__ pqb,
    const float* __restrict__ emb, const float* __restrict__ en,
    float* __restrict__ q) {
  __shared__ float xs[64 * 68];
  __shared__ _Float16 Ah[64 * 72];
  __shared__ _Float16 Al[64 * 72];
  __shared__ float zl[64 * 65];
  __shared__ float dred[4 * 64];
  __shared__ int   ired[4 * 64];
  __shared__ int   idxs[64];
  const int tid = threadIdx.x;
  const int w = tid >> 6, lane = tid & 63, lm = lane & 15, quad = lane >> 4;
  const int n = blockIdx.y, t0 = blockIdx.x * 64;
#pragma unroll
  for (int it = 0; it < 4; ++it) {
    int idx = it * 256 + tid;
    int row = idx >> 4, c4 = idx & 15;
    float4 v = *(const float4*)(sIn + ((size_t)n * 64 + row) * 1024 + t0 + c4 * 4);
    *(float4*)(&xs[row * 68 + c4 * 4]) = v;
  }
  __syncthreads();
#pragma unroll
  for (int it = 0; it < 16; ++it) {
    int slot = it * 256 + tid;
    int ci = slot & 63, t = slot >> 6;
    float v = fmaxf(xs[ci * 68 + t], 0.f);
    _Float16 h, l; splitf(v, h, l);
    Ah[t * 72 + ci] = h; Al[t * 72 + ci] = l;
  }
  __syncthreads();
  f32x4 a1[4], a2[4];
#pragma unroll
  for (int j = 0; j < 4; ++j)
#pragma unroll
    for (int r = 0; r < 4; ++r) { a1[j][r] = 0.f; a2[j][r] = 0.f; }
#pragma unroll
  for (int ks = 0; ks < 2; ++ks) {
    H8u ah, al;
    ah.i = *(const int4*)(&Ah[(w * 16 + lm) * 72 + ks * 32 + quad * 8]);
    al.i = *(const int4*)(&Al[(w * 16 + lm) * 72 + ks * 32 + quad * 8]);
#pragma unroll
    for (int j = 0; j < 4; ++j) {
      int col = j * 16 + lm;
      H8u bh, bl;
      bh.i = *(const int4*)(PQH + col * 64 + ks * 32 + quad * 8);
      bl.i = *(const int4*)(PQL + col * 64 + ks * 32 + quad * 8);
      a1[j] = __builtin_amdgcn_mfma_f32_16x16x32_f16(ah.h, bh.h, a1[j], 0,0,0);
      a2[j] = __builtin_amdgcn_mfma_f32_16x16x32_f16(ah.h, bl.h, a2[j], 0,0,0);
      a2[j] = __builtin_amdgcn_mfma_f32_16x16x32_f16(al.h, bh.h, a2[j], 0,0,0);
    }
  }
#pragma unroll
  for (int j = 0; j < 4; ++j) {
    int col = j * 16 + lm;
    float bv = pqb[col];
#pragma unroll
    for (int r = 0; r < 4; ++r) {
      int t = w * 16 + quad * 4 + r;
      zl[t * 65 + col] = a1[j][r] + a2[j][r] * INV2048 + bv;
    }
  }
  __syncthreads();
  int tt = tid & 63, cq = tid >> 6;
  float zv[64];
#pragma unroll
  for (int c = 0; c < 64; ++c) zv[c] = zl[tt * 65 + c];
  float best = 1e30f; int bidx = 0;
  for (int e = cq * 128; e < cq * 128 + 128; ++e) {
    const float* er = emb + (size_t)e * 64;
    float dot = 0.f;
#pragma unroll
    for (int c = 0; c < 64; ++c) dot = fmaf(zv[c], er[c], dot);
    float d = en[e] - 2.f * dot;
    if (d < best) { best = d; bidx = e; }
  }
  dred[cq * 64 + tt] = best;
  ired[cq * 64 + tt] = bidx;
  __syncthreads();
  if (cq == 0) {
    for (int j = 1; j < 4; ++j) {
      float d = dred[j * 64 + tt]; int i2 = ired[j * 64 + tt];
      if (d < best || (d == best && i2 < bidx)) { best = d; bidx = i2; }
    }
    idxs[tt] = bidx;
  }
  __syncthreads();
  for (int it = 0; it < 16; ++it) {
    int c = cq * 16 + it;
    q[((size_t)n * 64 + c) * 1024 + t0 + tt] = emb[(size_t)idxs[tt] * 64 + c];
  }
}

// ---------------------------------------------------------------------------
extern "C" void kernel_launch(void* const* d_in, const int* in_sizes, int n_in,
                              void* d_out, int out_size, void* d_ws, size_t ws_size,
                              hipStream_t stream) {
  const float* x        = (const float*)d_in[0];
  const float* enc_b1   = (const float*)d_in[2];
  const float* enc_b2   = (const float*)d_in[4];
  const float* enc_b3   = (const float*)d_in[6];
  const float* prevq_b  = (const float*)d_in[12];
  const float* emb      = (const float*)d_in[13];
  const float* dec_b1   = (const float*)d_in[15];
  const float* dect1_b  = (const float*)d_in[21];
  const float* dect2_b  = (const float*)d_in[23];
  float* out = (float*)d_out;

  WPtrs P;
  P.c1  = (const float*)d_in[1];  P.c2  = (const float*)d_in[3];
  P.c3  = (const float*)d_in[5];  P.er0a = (const float*)d_in[7];
  P.er0b = (const float*)d_in[8]; P.er1a = (const float*)d_in[9];
  P.er1b = (const float*)d_in[10]; P.pq = (const float*)d_in[11];
  P.dw1 = (const float*)d_in[14]; P.dr0a = (const float*)d_in[16];
  P.dr0b = (const float*)d_in[17]; P.dr1a = (const float*)d_in[18];
  P.dr1b = (const float*)d_in[19]; P.t1 = (const float*)d_in[20];
  P.t2  = (const float*)d_in[22];

  float* A  = (float*)d_ws;                   // 1M floats
  float* B  = A + (1u << 20);                 // 1M floats
  float* EN = B + (1u << 20);                 // 512 floats
  _Float16* WH = (_Float16*)(EN + 1024);      // WTOT f16
  _Float16* WL = WH + WTOT;
  float* PP = (float*)(WL + WTOT);            // conv1 split-K partial planes

  // conv1 split-K: plane = 16*32*2048 floats = 4 MB. Pick nparts by ws_size.
  const size_t baseBytes = (size_t)((char*)PP - (char*)d_ws);
  const size_t planeB = (size_t)16 * 32 * 2048 * 4;
  int nparts = 1;
  float* Pbuf = A;                            // nparts==1: reuse A directly
  if (ws_size >= baseBytes + 4 * planeB) { nparts = 4; Pbuf = PP; }
  else if (ws_size >= baseBytes + 2 * planeB) { nparts = 2; Pbuf = PP; }

  dim3 blk(256);
  prep_k<<<dim3((WTOT + 255) / 256), blk, 0, stream>>>(P, WH, WL);
  enorm_k<<<dim3(2), blk, 0, stream>>>(emb, EN);
  // encoder — conv1 writes raw split-K partials; conv2 sums + bias + relu
  conv1_k<<<dim3(32, 16, nparts), blk, 0, stream>>>(x, WH + OFF_C1, WL + OFF_C1,
                                                    Pbuf, 48 / nparts);
  gconv<32,128,4,2, false,true,true, false,false, true><<<dim3(32,16), blk, 0, stream>>>(
      Pbuf, WH+OFF_C2, WL+OFF_C2, enc_b2, nullptr, nullptr, B, 2048, 1024,
      enc_b1, nparts, 16 * 32 * 2048);
  gconv<64,256,4,1, false,false,true, false,false><<<dim3(32,16), blk, 0, stream>>>(
      B, WH+OFF_C3, WL+OFF_C3, enc_b3, nullptr, nullptr, A, 1024, 1024,
      nullptr, 1, 0);
  gconv<64,256,2,1, true,false,false, false,true><<<dim3(32,16), blk, 0, stream>>>(
      A, WH+OFF_ER0A, WL+OFF_ER0A, nullptr, WH+OFF_ER0B, WL+OFF_ER0B, B, 1024, 1024,
      nullptr, 1, 0);
  gconv<64,256,2,1, true,false,false, false,true><<<dim3(32,16), blk, 0, stream>>>(
      B, WH+OFF_ER1A, WL+OFF_ER1A, nullptr, WH+OFF_ER1B, WL+OFF_ER1B, A, 1024, 1024,
      nullptr, 1, 0);
  // VQ (prevq + relu fused)
  vq_fused<<<dim3(16,16), blk, 0, stream>>>(A, WH+OFF_PQ, WL+OFF_PQ, prevq_b, emb, EN, B);
  // decoder
  gconv<64,256,4,1, false,false,true, false,false><<<dim3(32,16), blk, 0, stream>>>(
      B, WH+OFF_DW1, WL+OFF_DW1, dec_b1, nullptr, nullptr, A, 1024, 1024,
      nullptr, 1, 0);
  gconv<64,256,2,1, true,false,false, false,true><<<dim3(32,16), blk, 0, stream>>>(
      A, WH+OFF_DR0A, WL+OFF_DR0A, nullptr, WH+OFF_DR0B, WL+OFF_DR0B, B, 1024, 1024,
      nullptr, 1, 0);
  gconv<64,256,2,1, true,false,false, false,true><<<dim3(32,16), blk, 0, stream>>>(
      B, WH+OFF_DR1A, WL+OFF_DR1A, nullptr, WH+OFF_DR1B, WL+OFF_DR1B, A, 1024, 1024,
      nullptr, 1, 0);
  gconv<64,256,4,1, true,true,true, true,false><<<dim3(32,16), blk, 0, stream>>>(
      A, WH+OFF_T1, WL+OFF_T1, dect1_b, nullptr, nullptr, B, 1024, 2048,
      nullptr, 1, 0);
  gconv<32,128,8,1, false,false,true, true,false><<<dim3(64,16), blk, 0, stream>>>(
      B, WH+OFF_T2, WL+OFF_T2, dect2_b, nullptr, nullptr, out, 2048, 4096,
      nullptr, 1, 0);
}

// Round 5
// 549.458 us; speedup vs baseline: 1.2515x; 1.2515x over previous
//
#include <hip/hip_runtime.h>

// ---------------------------------------------------------------------------
// VQ-VAE forward — split-fp16 MFMA everywhere.
// x = h + l*2^-11 (l prescaled by 2^11), w likewise; acc1 = h*wh,
// acc2 = h*wl + l*wh; result = acc1 + acc2/2048.  (fp32-accurate)
// Verified MFMA mapping: A[m=lane&15][k=quad*8+j] (8 consecutive k),
// B rows [n][kk] (8 consecutive kk at col n=lane&15), D col=lane&15,
// row=quad*4+reg.  kk = ci*4 + tap, tap padded to 4 with zero weights.
// R3 lesson: NEVER index register arrays with runtime values.
// R6 lesson: direct-from-global fragment gathers are TA/L1 SEGMENT-bound
// (B int4 at 6KB stride = 16 seg/instr). Occupancy alone gave only 9%.
// R7 lesson: LDS-staging A but keeping global B loads INSIDE the barriered
// chunk serialized every chunk on vmcnt(B); launch_bounds(256,6) squeeze
// (VGPR=40) added ~48MB/48MB of phantom fetch/write traffic (scratch).
// R8 change: B staged through LDS too. conv1 weights re-prepped to
// [kkblk][col][kkin] so a chunk's B slice is contiguous 8KB; staged
// coalesced (1 int4/thread for H and L), double-buffered, XOR-swizzled
// (slot ^ col&7, write AND read side) against the 128B-row bank
// degeneracy. Compute phase now touches ONLY LDS + MFMA. launch_bounds
// (256,4), nparts=2 (1024 blocks = exactly 4 blocks/CU at 33.8KB LDS).
// ---------------------------------------------------------------------------

typedef _Float16 half8 __attribute__((ext_vector_type(8)));
typedef float f32x4 __attribute__((ext_vector_type(4)));
union H8u { half8 h; int4 i; };
union P4u { _Float16 e[4]; int2 u; };

__device__ __forceinline__ void splitf(float v, _Float16& h, _Float16& l) {
  h = (_Float16)v; l = (_Float16)((v - (float)h) * 2048.0f);
}
#define INV2048 (1.0f / 2048.0f)

// ---- prepped-weight layout offsets (f16 elements) ----
#define OFF_C1   0        // conv1  [48 kkblk][32 col][64 kkin]
#define OFF_C2   98304    // conv2  [64][128]
#define OFF_C3   106496   // conv3  [64][256]
#define OFF_ER0A 122880   // enc r0 conv3 [32][256]
#define OFF_ER0B 131072   // enc r0 1x1   [64][32]
#define OFF_ER1A 133120
#define OFF_ER1B 141312
#define OFF_PQ   143360   // prevq [64][64]
#define OFF_DW1  147456   // dec conv1 [64][256]
#define OFF_DR0A 163840
#define OFF_DR0B 172032
#define OFF_DR1A 174080
#define OFF_DR1B 182272
#define OFF_T1   184320   // convT1 [64=par*32+co][256]
#define OFF_T2   200704   // convT2 [128=par*64+co][128]
#define WTOT     217088

struct WPtrs {
  const float *c1, *c2, *c3, *er0a, *er0b, *er1a, *er1b, *pq,
              *dw1, *dr0a, *dr0b, *dr1a, *dr1b, *t1, *t2;
};

__device__ __forceinline__ int tpose_kt(int par, int tap) {
  if (par == 0) { if (tap == 0) return 3; if (tap == 1) return 1; }
  else          { if (tap == 1) return 2; if (tap == 2) return 0; }
  return -1;
}

__global__ __launch_bounds__(256) void prep_k(WPtrs P, _Float16* __restrict__ WH,
                                              _Float16* __restrict__ WL) {
  int s = blockIdx.x * 256 + threadIdx.x;
  if (s >= WTOT) return;
  float v = 0.f;
  if (s < OFF_C2) {
    // conv1: [kkblk][col][kkin] (k-major blocks for contiguous LDS staging)
    int t = s, kkblk = t >> 11, rem = t & 2047, col = rem >> 6, kkin = rem & 63;
    int kk = kkblk * 64 + kkin;
    v = P.c1[col * 3072 + kk];   // == (col*768 + (kk>>2))*4 + (kk&3)
  } else if (s < OFF_C3) {
    int t = s - OFF_C2, co = t >> 7, kk = t & 127;
    v = P.c2[(co * 32 + (kk >> 2)) * 4 + (kk & 3)];
  } else if (s < OFF_ER0A) {
    int t = s - OFF_C3, co = t >> 8, kk = t & 255, tap = kk & 3;
    if (tap < 3) v = P.c3[(co * 64 + (kk >> 2)) * 3 + tap];
  } else if (s < OFF_ER0B) {
    int t = s - OFF_ER0A, co = t >> 8, kk = t & 255, tap = kk & 3;
    if (tap < 3) v = P.er0a[(co * 64 + (kk >> 2)) * 3 + tap];
  } else if (s < OFF_ER1A) {
    int t = s - OFF_ER0B; v = P.er0b[t];
  } else if (s < OFF_ER1B) {
    int t = s - OFF_ER1A, co = t >> 8, kk = t & 255, tap = kk & 3;
    if (tap < 3) v = P.er1a[(co * 64 + (kk >> 2)) * 3 + tap];
  } else if (s < OFF_PQ) {
    int t = s - OFF_ER1B; v = P.er1b[t];
  } else if (s < OFF_DW1) {
    int t = s - OFF_PQ; v = P.pq[t];
  } else if (s < OFF_DR0A) {
    int t = s - OFF_DW1, co = t >> 8, kk = t & 255, tap = kk & 3;
    if (tap < 3) v = P.dw1[(co * 64 + (kk >> 2)) * 3 + tap];
  } else if (s < OFF_DR0B) {
    int t = s - OFF_DR0A, co = t >> 8, kk = t & 255, tap = kk & 3;
    if (tap < 3) v = P.dr0a[(co * 64 + (kk >> 2)) * 3 + tap];
  } else if (s < OFF_DR1A) {
    int t = s - OFF_DR0B; v = P.dr0b[t];
  } else if (s < OFF_DR1B) {
    int t = s - OFF_DR1A, co = t >> 8, kk = t & 255, tap = kk & 3;
    if (tap < 3) v = P.dr1a[(co * 64 + (kk >> 2)) * 3 + tap];
  } else if (s < OFF_T1) {
    int t = s - OFF_DR1B; v = P.dr1b[t];
  } else if (s < OFF_T2) {
    int t = s - OFF_T1, nn = t >> 8, kk = t & 255;
    int par = nn >> 5, co = nn & 31, ci = kk >> 2;
    int kt = tpose_kt(par, kk & 3);
    if (kt >= 0) v = P.t1[(ci * 32 + co) * 4 + kt];
  } else {
    int t = s - OFF_T2, nn = t >> 7, kk = t & 127;
    int par = nn >> 6, co = nn & 63, ci = kk >> 2;
    int kt = tpose_kt(par, kk & 3);
    if (kt >= 0) v = P.t2[(ci * 64 + co) * 4 + kt];
  }
  _Float16 h, l; splitf(v, h, l);
  WH[s] = h; WL[s] = l;
}

// --------------------------- conv1 (768->32, k4 s2) -------------------------
// LDS-staged A AND B, single-barrier double-buffered pipeline, SPLIT-K.
// Block = 4 waves, M-tile 64 (wave w owns rows r = w*16+lm). A chunk = 16
// channels x 132 positions (split-once h/l planes, window read = stride-1
// dwords). B chunk = [32 col][64 kkin] slice, staged coalesced (1 int4 per
// thread for H and L), XOR-swizzled slot^(col&7) on both write and read.
// Compute phase touches only LDS + MFMA. blockIdx.z = kpart; raw fp32
// partials -> Pout planes (PSUM in conv2 sums + bias + relu).
__global__ __launch_bounds__(256, 4) void conv1_k(
    const float* __restrict__ x, const _Float16* __restrict__ WH,
    const _Float16* __restrict__ WL, float* __restrict__ Pout, int cpp) {
  __shared__ _Float16 Hs[2][16 * 136];
  __shared__ _Float16 Ls[2][16 * 136];
  __shared__ _Float16 Bhs[2][32 * 64];
  __shared__ _Float16 Bls[2][32 * 64];
  const int tid = threadIdx.x;
  const int w = tid >> 6, lane = tid & 63, lm = lane & 15, quad = lane >> 4;
  const int m0 = blockIdx.x * 64, n = blockIdx.y, kpart = blockIdx.z;
  const int r = w * 16 + lm;                  // wave-local output row 0..63
  const int pb = 2 * m0 - 1;                  // global pos of local q=0
  const float* xn = x + (size_t)n * 768 * 4096;
  // A staging slots: 528 = 16 rows x 33 float4; slot2 only for tid<16
  const int r0s = tid / 33, c0s = tid % 33;
  const int r1s = (256 + tid) / 33, c1s = (256 + tid) % 33;
  const int r2s = (512 + tid) / 33, c2s = (512 + tid) % 33;
  // B staging: thread -> (col, slot); LDS f16 idx = col*64 + (slot^(col&7))*8
  const int bcol = tid >> 3, bslot = tid & 7;
  const int bdst = bcol * 64 + ((bslot ^ (bcol & 7)) << 3);

  f32x4 acc1[2], acc2[2];
#pragma unroll
  for (int j = 0; j < 2; ++j)
#pragma unroll
    for (int rr = 0; rr < 4; ++rr) { acc1[j][rr] = 0.f; acc2[j][rr] = 0.f; }

  const int cb0 = kpart * cpp;
  float4 sv0, sv1, sv2;
  H8u bhv, blv;

#define C1_LD1(SV, RS, CS) { \
    int p0 = pb + 4 * (CS); \
    const float* rp = xn + (size_t)(chb + (RS)) * 4096; \
    if (p0 >= 0 && p0 + 3 < 4096) SV = *(const float4*)(rp + p0); \
    else { \
      SV.x = (p0   >= 0 && p0   < 4096) ? rp[p0]   : 0.f; \
      SV.y = (p0+1 >= 0 && p0+1 < 4096) ? rp[p0+1] : 0.f; \
      SV.z = (p0+2 >= 0 && p0+2 < 4096) ? rp[p0+2] : 0.f; \
      SV.w = (p0+3 >= 0 && p0+3 < 4096) ? rp[p0+3] : 0.f; } }

#define C1_LOAD(cc) { \
    int chb = (cb0 + (cc)) * 16; \
    C1_LD1(sv0, r0s, c0s) \
    C1_LD1(sv1, r1s, c1s) \
    if (tid < 16) C1_LD1(sv2, r2s, c2s) \
    bhv.i = *(const int4*)(WH + (size_t)(cb0 + (cc)) * 2048 + tid * 8); \
    blv.i = *(const int4*)(WL + (size_t)(cb0 + (cc)) * 2048 + tid * 8); }

#define C1_WR1(SV, RS, CS, B) { \
    P4u ph, pl; \
    splitf(SV.x, ph.e[0], pl.e[0]); splitf(SV.y, ph.e[1], pl.e[1]); \
    splitf(SV.z, ph.e[2], pl.e[2]); splitf(SV.w, ph.e[3], pl.e[3]); \
    *(int2*)(&Hs[B][(RS) * 136 + 4 * (CS)]) = ph.u; \
    *(int2*)(&Ls[B][(RS) * 136 + 4 * (CS)]) = pl.u; }

#define C1_WRITE(B) { \
    C1_WR1(sv0, r0s, c0s, B) \
    C1_WR1(sv1, r1s, c1s, B) \
    if (tid < 16) C1_WR1(sv2, r2s, c2s, B) \
    *(int4*)(&Bhs[B][bdst]) = bhv.i; \
    *(int4*)(&Bls[B][bdst]) = blv.i; }

#define C1_COMP(B) { \
    const uint* Hdw = (const uint*)(&Hs[B][0]); \
    const uint* Ldw = (const uint*)(&Ls[B][0]); \
    _Pragma("unroll") \
    for (int ks = 0; ks < 2; ++ks) { \
      const int ci0 = ks * 8 + quad * 2; \
      const int bse = ci0 * 68 + r; \
      H8u ah, al; \
      ah.i.x = Hdw[bse];      ah.i.y = Hdw[bse + 1]; \
      ah.i.z = Hdw[bse + 68]; ah.i.w = Hdw[bse + 69]; \
      al.i.x = Ldw[bse];      al.i.y = Ldw[bse + 1]; \
      al.i.z = Ldw[bse + 68]; al.i.w = Ldw[bse + 69]; \
      const int sA = ((4 * ks + quad) ^ (lm & 7)) << 3; \
      H8u b0h, b0l, b1h, b1l; \
      b0h.i = *(const int4*)(&Bhs[B][lm * 64 + sA]); \
      b0l.i = *(const int4*)(&Bls[B][lm * 64 + sA]); \
      b1h.i = *(const int4*)(&Bhs[B][(16 + lm) * 64 + sA]); \
      b1l.i = *(const int4*)(&Bls[B][(16 + lm) * 64 + sA]); \
      acc1[0] = __builtin_amdgcn_mfma_f32_16x16x32_f16(ah.h, b0h.h, acc1[0], 0,0,0); \
      acc2[0] = __builtin_amdgcn_mfma_f32_16x16x32_f16(ah.h, b0l.h, acc2[0], 0,0,0); \
      acc2[0] = __builtin_amdgcn_mfma_f32_16x16x32_f16(al.h, b0h.h, acc2[0], 0,0,0); \
      acc1[1] = __builtin_amdgcn_mfma_f32_16x16x32_f16(ah.h, b1h.h, acc1[1], 0,0,0); \
      acc2[1] = __builtin_amdgcn_mfma_f32_16x16x32_f16(ah.h, b1l.h, acc2[1], 0,0,0); \
      acc2[1] = __builtin_amdgcn_mfma_f32_16x16x32_f16(al.h, b1h.h, acc2[1], 0,0,0); \
    } }

  // prologue: stage chunk 0 into buffer 0
  C1_LOAD(0);
  C1_WRITE(0);
  __syncthreads();
#pragma unroll 1
  for (int cc = 0; cc < cpp; ++cc) {
    const int cur = cc & 1;
    if (cc + 1 < cpp) C1_LOAD(cc + 1);   // issue next-chunk globals early
    C1_COMP(cur);                        // LDS + MFMA only
    if (cc + 1 < cpp) C1_WRITE(cur ^ 1); // write next buffer late
    __syncthreads();                     // one barrier per chunk
  }

  // epilogue: raw partial (bias/relu deferred to conv2's staging)
#pragma unroll
  for (int j = 0; j < 2; ++j) {
    int col = j * 16 + lm;
    float4 o;
    o.x = acc1[j][0] + acc2[j][0] * INV2048;
    o.y = acc1[j][1] + acc2[j][1] * INV2048;
    o.z = acc1[j][2] + acc2[j][2] * INV2048;
    o.w = acc1[j][3] + acc2[j][3] * INV2048;
    *(float4*)(Pout + (size_t)kpart * (16 * 32 * 2048)
               + ((size_t)n * 32 + col) * 2048 + m0 + w * 16 + quad * 4) = o;
  }
#undef C1_LD1
#undef C1_LOAD
#undef C1_WR1
#undef C1_WRITE
#undef C1_COMP
}

// ------------------- generic one-shot MFMA conv (M-tile 32) -----------------
// PSUM: input is `nparts` raw partial planes (stride pplane floats); staging
// sums them, adds inbias[row], applies relu — in-range elements only.
template<int CI, int KP, int NT, int STRIDE,
         bool RELU_IN, bool RELU_OUT, bool BIAS, bool TPOSE, bool RESBLK,
         bool PSUM = false>
__global__ __launch_bounds__(256) void gconv(
    const float* __restrict__ in, const _Float16* __restrict__ WH,
    const _Float16* __restrict__ WL, const float* __restrict__ bias,
    const _Float16* __restrict__ W2H, const _Float16* __restrict__ W2L,
    float* __restrict__ out, int Lin, int Lout,
    const float* __restrict__ inbias, int nparts, int pplane) {
  constexpr int CP = 32 * STRIDE + 4;
  constexpr int CP4 = CP / 4;
  constexpr int AP = KP + 8;
  constexpr int KS = KP / 32;
  constexpr int NTW = (NT == 2) ? 1 : NT / 2;
  __shared__ float xs[CI * CP];
  __shared__ _Float16 Ah[32 * AP];
  __shared__ _Float16 Al[32 * AP];
  __shared__ _Float16 A2h[RESBLK ? 32 * 40 : 1];
  __shared__ _Float16 A2l[RESBLK ? 32 * 40 : 1];
  const int tid = threadIdx.x;
  const int w = tid >> 6, lane = tid & 63, lm = lane & 15, quad = lane >> 4;
  const int mt = w >> 1, ntb = (w & 1) * NTW;
  const int m0 = blockIdx.x * 32, n = blockIdx.y;
  const int base = m0 * STRIDE - 1;
  const float* inN = in + (size_t)n * CI * Lin;
  constexpr int SLOTS = CI * CP4;
#pragma unroll
  for (int it = 0; it < (SLOTS + 255) / 256; ++it) {
    int idx = it * 256 + tid;
    if (idx < SLOTS) {
      int row = idx / CP4, c4 = idx % CP4;
      int p0 = base + c4 * 4;
      const float* rp = inN + (size_t)row * Lin;
      float4 v;
      if (PSUM) {
        v.x = 0.f; v.y = 0.f; v.z = 0.f; v.w = 0.f;
        bool i0 = (p0   >= 0 && p0   < Lin);
        bool i1 = (p0+1 >= 0 && p0+1 < Lin);
        bool i2 = (p0+2 >= 0 && p0+2 < Lin);
        bool i3 = (p0+3 >= 0 && p0+3 < Lin);
        bool full = (p0 >= 0 && p0 + 3 < Lin);
        for (int p = 0; p < nparts; ++p) {
          const float* rpp = rp + (size_t)p * pplane;
          if (full) {
            float4 t = *(const float4*)(rpp + p0);
            v.x += t.x; v.y += t.y; v.z += t.z; v.w += t.w;
          } else {
            if (i0) v.x += rpp[p0];
            if (i1) v.y += rpp[p0+1];
            if (i2) v.z += rpp[p0+2];
            if (i3) v.w += rpp[p0+3];
          }
        }
        float bv = inbias[row];
        v.x = i0 ? fmaxf(v.x + bv, 0.f) : 0.f;
        v.y = i1 ? fmaxf(v.y + bv, 0.f) : 0.f;
        v.z = i2 ? fmaxf(v.z + bv, 0.f) : 0.f;
        v.w = i3 ? fmaxf(v.w + bv, 0.f) : 0.f;
      } else {
        if (p0 >= 0 && p0 + 3 < Lin) v = *(const float4*)(rp + p0);
        else {
          v.x = (p0   >= 0 && p0   < Lin) ? rp[p0]   : 0.f;
          v.y = (p0+1 >= 0 && p0+1 < Lin) ? rp[p0+1] : 0.f;
          v.z = (p0+2 >= 0 && p0+2 < Lin) ? rp[p0+2] : 0.f;
          v.w = (p0+3 >= 0 && p0+3 < Lin) ? rp[p0+3] : 0.f;
        }
      }
      *(float4*)(&xs[row * CP + c4 * 4]) = v;
    }
  }
  __syncthreads();
#pragma unroll
  for (int it = 0; it < (32 * CI) / 256; ++it) {
    int slot = it * 256 + tid;
    int ci = slot & (CI - 1), m = slot / CI;
    const float* xr = &xs[ci * CP + STRIDE * m];
    float a0 = xr[0], a1 = xr[1], a2 = xr[2], a3 = xr[3];
    if (RELU_IN) { a0 = fmaxf(a0,0.f); a1 = fmaxf(a1,0.f);
                   a2 = fmaxf(a2,0.f); a3 = fmaxf(a3,0.f); }
    P4u ph, pl;
    splitf(a0, ph.e[0], pl.e[0]); splitf(a1, ph.e[1], pl.e[1]);
    splitf(a2, ph.e[2], pl.e[2]); splitf(a3, ph.e[3], pl.e[3]);
    *(int2*)(&Ah[m * AP + ci * 4]) = ph.u;
    *(int2*)(&Al[m * AP + ci * 4]) = pl.u;
  }
  __syncthreads();
  f32x4 acc1[NTW], acc2[NTW];
#pragma unroll
  for (int j = 0; j < NTW; ++j)
#pragma unroll
    for (int r = 0; r < 4; ++r) { acc1[j][r] = 0.f; acc2[j][r] = 0.f; }
  H8u bh[2][NTW], bl[2][NTW];
#pragma unroll
  for (int j = 0; j < NTW; ++j) {
    int col = (ntb + j) * 16 + lm;
    bh[0][j].i = *(const int4*)(WH + (size_t)col * KP + quad * 8);
    bl[0][j].i = *(const int4*)(WL + (size_t)col * KP + quad * 8);
  }
#pragma unroll
  for (int ks = 0; ks < KS; ++ks) {
    int cur = ks & 1;                      // static after full unroll
    if (ks + 1 < KS) {
#pragma unroll
      for (int j = 0; j < NTW; ++j) {
        int col = (ntb + j) * 16 + lm;
        bh[cur ^ 1][j].i = *(const int4*)(WH + (size_t)col * KP + (ks+1) * 32 + quad * 8);
        bl[cur ^ 1][j].i = *(const int4*)(WL + (size_t)col * KP + (ks+1) * 32 + quad * 8);
      }
    }
    H8u ah, al;
    ah.i = *(const int4*)(&Ah[(mt * 16 + lm) * AP + ks * 32 + quad * 8]);
    al.i = *(const int4*)(&Al[(mt * 16 + lm) * AP + ks * 32 + quad * 8]);
#pragma unroll
    for (int j = 0; j < NTW; ++j) {
      acc1[j] = __builtin_amdgcn_mfma_f32_16x16x32_f16(ah.h, bh[cur][j].h, acc1[j], 0,0,0);
      acc2[j] = __builtin_amdgcn_mfma_f32_16x16x32_f16(ah.h, bl[cur][j].h, acc2[j], 0,0,0);
      acc2[j] = __builtin_amdgcn_mfma_f32_16x16x32_f16(al.h, bh[cur][j].h, acc2[j], 0,0,0);
    }
  }
  if (RESBLK) {
    int co2 = (w & 1) * 16 + lm;
#pragma unroll
    for (int r = 0; r < 4; ++r) {
      float hv = fmaxf(acc1[0][r] + acc2[0][r] * INV2048, 0.f);
      _Float16 hh, hl; splitf(hv, hh, hl);
      int m = mt * 16 + quad * 4 + r;
      A2h[m * 40 + co2] = hh; A2l[m * 40 + co2] = hl;
    }
    __syncthreads();
    f32x4 c1[2], c2[2];
#pragma unroll
    for (int j = 0; j < 2; ++j)
#pragma unroll
      for (int r = 0; r < 4; ++r) { c1[j][r] = 0.f; c2[j][r] = 0.f; }
    H8u a2h, a2l;
    a2h.i = *(const int4*)(&A2h[(mt * 16 + lm) * 40 + quad * 8]);
    a2l.i = *(const int4*)(&A2l[(mt * 16 + lm) * 40 + quad * 8]);
    int ntb2 = (w & 1) * 2;
#pragma unroll
    for (int j = 0; j < 2; ++j) {
      int col = (ntb2 + j) * 16 + lm;
      H8u wbh, wbl;
      wbh.i = *(const int4*)(W2H + col * 32 + quad * 8);
      wbl.i = *(const int4*)(W2L + col * 32 + quad * 8);
      c1[j] = __builtin_amdgcn_mfma_f32_16x16x32_f16(a2h.h, wbh.h, c1[j], 0,0,0);
      c2[j] = __builtin_amdgcn_mfma_f32_16x16x32_f16(a2h.h, wbl.h, c2[j], 0,0,0);
      c2[j] = __builtin_amdgcn_mfma_f32_16x16x32_f16(a2l.h, wbh.h, c2[j], 0,0,0);
    }
#pragma unroll
    for (int j = 0; j < 2; ++j) {
      int col = (ntb2 + j) * 16 + lm;
      float4 o;
#pragma unroll
      for (int r = 0; r < 4; ++r) {
        int m = mt * 16 + quad * 4 + r;
        float res = xs[col * CP + m + 1];
        ((float*)&o)[r] = res + c1[j][r] + c2[j][r] * INV2048;
      }
      *(float4*)(out + ((size_t)n * 64 + col) * Lout + m0 + mt * 16 + quad * 4) = o;
    }
  } else {
    constexpr int CO = TPOSE ? NT * 8 : NT * 16;
#pragma unroll
    for (int j = 0; j < NTW; ++j) {
      int col = (ntb + j) * 16 + lm;
      int par = TPOSE ? (col / CO) : 0;
      int co  = TPOSE ? (col % CO) : col;
      float bv = BIAS ? bias[co] : 0.f;
      float vr[4];
#pragma unroll
      for (int r = 0; r < 4; ++r) {
        float v = acc1[j][r] + acc2[j][r] * INV2048 + bv;
        vr[r] = RELU_OUT ? fmaxf(v, 0.f) : v;
      }
      if (TPOSE) {
#pragma unroll
        for (int r = 0; r < 4; ++r) {
          int m = m0 + mt * 16 + quad * 4 + r;
          out[((size_t)n * CO + co) * Lout + 2 * m + par] = vr[r];
        }
      } else {
        float4 o; o.x = vr[0]; o.y = vr[1]; o.z = vr[2]; o.w = vr[3];
        *(float4*)(out + ((size_t)n * CO + co) * Lout + m0 + mt * 16 + quad * 4) = o;
      }
    }
  }
}

// ------------------------------ codebook norms ------------------------------
__global__ void enorm_k(const float* __restrict__ emb, float* __restrict__ en) {
  int e = blockIdx.x * blockDim.x + threadIdx.x;
  if (e >= 512) return;
  float s = 0.f;
  const float* r = emb + (size_t)e * 64;
  for (int c = 0; c < 64; ++c) s = fmaf(r[c], r[c], s);
  en[e] = s;
}

// ------------------ fused prevq (1x1, relu-in) + VQ -------------------------
__global__ __launch_bounds__(256) void vq_fused(
    const float* __restrict__ sIn, const _Float16* __restrict__ PQH,
    const _Float16* __restrict__ PQL, const float* __restrict__ pqb,
    const float* __restrict__ emb, const float* __restrict__ en,
    float* __restrict__ q) {
  __shared__ float xs[64 * 68];
  __shared__ _Float16 Ah[64 * 72];
  __shared__ _Float16 Al[64 * 72];
  __shared__ float zl[64 * 65];
  __shared__ float dred[4 * 64];
  __shared__ int   ired[4 * 64];
  __shared__ int   idxs[64];
  const int tid = threadIdx.x;
  const int w = tid >> 6, lane = tid & 63, lm = lane & 15, quad = lane >> 4;
  const int n = blockIdx.y, t0 = blockIdx.x * 64;
#pragma unroll
  for (int it = 0; it < 4; ++it) {
    int idx = it * 256 + tid;
    int row = idx >> 4, c4 = idx & 15;
    float4 v = *(const float4*)(sIn + ((size_t)n * 64 + row) * 1024 + t0 + c4 * 4);
    *(float4*)(&xs[row * 68 + c4 * 4]) = v;
  }
  __syncthreads();
#pragma unroll
  for (int it = 0; it < 16; ++it) {
    int slot = it * 256 + tid;
    int ci = slot & 63, t = slot >> 6;
    float v = fmaxf(xs[ci * 68 + t], 0.f);
    _Float16 h, l; splitf(v, h, l);
    Ah[t * 72 + ci] = h; Al[t * 72 + ci] = l;
  }
  __syncthreads();
  f32x4 a1[4], a2[4];
#pragma unroll
  for (int j = 0; j < 4; ++j)
#pragma unroll
    for (int r = 0; r < 4; ++r) { a1[j][r] = 0.f; a2[j][r] = 0.f; }
#pragma unroll
  for (int ks = 0; ks < 2; ++ks) {
    H8u ah, al;
    ah.i = *(const int4*)(&Ah[(w * 16 + lm) * 72 + ks * 32 + quad * 8]);
    al.i = *(const int4*)(&Al[(w * 16 + lm) * 72 + ks * 32 + quad * 8]);
#pragma unroll
    for (int j = 0; j < 4; ++j) {
      int col = j * 16 + lm;
      H8u bh, bl;
      bh.i = *(const int4*)(PQH + col * 64 + ks * 32 + quad * 8);
      bl.i = *(const int4*)(PQL + col * 64 + ks * 32 + quad * 8);
      a1[j] = __builtin_amdgcn_mfma_f32_16x16x32_f16(ah.h, bh.h, a1[j], 0,0,0);
      a2[j] = __builtin_amdgcn_mfma_f32_16x16x32_f16(ah.h, bl.h, a2[j], 0,0,0);
      a2[j] = __builtin_amdgcn_mfma_f32_16x16x32_f16(al.h, bh.h, a2[j], 0,0,0);
    }
  }
#pragma unroll
  for (int j = 0; j < 4; ++j) {
    int col = j * 16 + lm;
    float bv = pqb[col];
#pragma unroll
    for (int r = 0; r < 4; ++r) {
      int t = w * 16 + quad * 4 + r;
      zl[t * 65 + col] = a1[j][r] + a2[j][r] * INV2048 + bv;
    }
  }
  __syncthreads();
  int tt = tid & 63, cq = tid >> 6;
  float zv[64];
#pragma unroll
  for (int c = 0; c < 64; ++c) zv[c] = zl[tt * 65 + c];
  float best = 1e30f; int bidx = 0;
  for (int e = cq * 128; e < cq * 128 + 128; ++e) {
    const float* er = emb + (size_t)e * 64;
    float dot = 0.f;
#pragma unroll
    for (int c = 0; c < 64; ++c) dot = fmaf(zv[c], er[c], dot);
    float d = en[e] - 2.f * dot;
    if (d < best) { best = d; bidx = e; }
  }
  dred[cq * 64 + tt] = best;
  ired[cq * 64 + tt] = bidx;
  __syncthreads();
  if (cq == 0) {
    for (int j = 1; j < 4; ++j) {
      float d = dred[j * 64 + tt]; int i2 = ired[j * 64 + tt];
      if (d < best || (d == best && i2 < bidx)) { best = d; bidx = i2; }
    }
    idxs[tt] = bidx;
  }
  __syncthreads();
  for (int it = 0; it < 16; ++it) {
    int c = cq * 16 + it;
    q[((size_t)n * 64 + c) * 1024 + t0 + tt] = emb[(size_t)idxs[tt] * 64 + c];
  }
}

// ---------------------------------------------------------------------------
extern "C" void kernel_launch(void* const* d_in, const int* in_sizes, int n_in,
                              void* d_out, int out_size, void* d_ws, size_t ws_size,
                              hipStream_t stream) {
  const float* x        = (const float*)d_in[0];
  const float* enc_b1   = (const float*)d_in[2];
  const float* enc_b2   = (const float*)d_in[4];
  const float* enc_b3   = (const float*)d_in[6];
  const float* prevq_b  = (const float*)d_in[12];
  const float* emb      = (const float*)d_in[13];
  const float* dec_b1   = (const float*)d_in[15];
  const float* dect1_b  = (const float*)d_in[21];
  const float* dect2_b  = (const float*)d_in[23];
  float* out = (float*)d_out;

  WPtrs P;
  P.c1  = (const float*)d_in[1];  P.c2  = (const float*)d_in[3];
  P.c3  = (const float*)d_in[5];  P.er0a = (const float*)d_in[7];
  P.er0b = (const float*)d_in[8]; P.er1a = (const float*)d_in[9];
  P.er1b = (const float*)d_in[10]; P.pq = (const float*)d_in[11];
  P.dw1 = (const float*)d_in[14]; P.dr0a = (const float*)d_in[16];
  P.dr0b = (const float*)d_in[17]; P.dr1a = (const float*)d_in[18];
  P.dr1b = (const float*)d_in[19]; P.t1 = (const float*)d_in[20];
  P.t2  = (const float*)d_in[22];

  float* A  = (float*)d_ws;                   // 1M floats
  float* B  = A + (1u << 20);                 // 1M floats
  float* EN = B + (1u << 20);                 // 512 floats
  _Float16* WH = (_Float16*)(EN + 1024);      // WTOT f16
  _Float16* WL = WH + WTOT;
  float* PP = (float*)(WL + WTOT);            // conv1 split-K partial planes

  // conv1 split-K: plane = 16*32*2048 floats = 4 MB. Pick nparts by ws_size.
  const size_t baseBytes = (size_t)((char*)PP - (char*)d_ws);
  const size_t planeB = (size_t)16 * 32 * 2048 * 4;
  int nparts = 1;
  float* Pbuf = A;                            // nparts==1: reuse A directly
  if (ws_size >= baseBytes + 2 * planeB) { nparts = 2; Pbuf = PP; }

  dim3 blk(256);
  prep_k<<<dim3((WTOT + 255) / 256), blk, 0, stream>>>(P, WH, WL);
  enorm_k<<<dim3(2), blk, 0, stream>>>(emb, EN);
  // encoder — conv1 writes raw split-K partials; conv2 sums + bias + relu
  conv1_k<<<dim3(32, 16, nparts), blk, 0, stream>>>(x, WH + OFF_C1, WL + OFF_C1,
                                                    Pbuf, 48 / nparts);
  gconv<32,128,4,2, false,true,true, false,false, true><<<dim3(32,16), blk, 0, stream>>>(
      Pbuf, WH+OFF_C2, WL+OFF_C2, enc_b2, nullptr, nullptr, B, 2048, 1024,
      enc_b1, nparts, 16 * 32 * 2048);
  gconv<64,256,4,1, false,false,true, false,false><<<dim3(32,16), blk, 0, stream>>>(
      B, WH+OFF_C3, WL+OFF_C3, enc_b3, nullptr, nullptr, A, 1024, 1024,
      nullptr, 1, 0);
  gconv<64,256,2,1, true,false,false, false,true><<<dim3(32,16), blk, 0, stream>>>(
      A, WH+OFF_ER0A, WL+OFF_ER0A, nullptr, WH+OFF_ER0B, WL+OFF_ER0B, B, 1024, 1024,
      nullptr, 1, 0);
  gconv<64,256,2,1, true,false,false, false,true><<<dim3(32,16), blk, 0, stream>>>(
      B, WH+OFF_ER1A, WL+OFF_ER1A, nullptr, WH+OFF_ER1B, WL+OFF_ER1B, A, 1024, 1024,
      nullptr, 1, 0);
  // VQ (prevq + relu fused)
  vq_fused<<<dim3(16,16), blk, 0, stream>>>(A, WH+OFF_PQ, WL+OFF_PQ, prevq_b, emb, EN, B);
  // decoder
  gconv<64,256,4,1, false,false,true, false,false><<<dim3(32,16), blk, 0, stream>>>(
      B, WH+OFF_DW1, WL+OFF_DW1, dec_b1, nullptr, nullptr, A, 1024, 1024,
      nullptr, 1, 0);
  gconv<64,256,2,1, true,false,false, false,true><<<dim3(32,16), blk, 0, stream>>>(
      A, WH+OFF_DR0A, WL+OFF_DR0A, nullptr, WH+OFF_DR0B, WL+OFF_DR0B, B, 1024, 1024,
      nullptr, 1, 0);
  gconv<64,256,2,1, true,false,false, false,true><<<dim3(32,16), blk, 0, stream>>>(
      B, WH+OFF_DR1A, WL+OFF_DR1A, nullptr, WH+OFF_DR1B, WL+OFF_DR1B, A, 1024, 1024,
      nullptr, 1, 0);
  gconv<64,256,4,1, true,true,true, true,false><<<dim3(32,16), blk, 0, stream>>>(
      A, WH+OFF_T1, WL+OFF_T1, dect1_b, nullptr, nullptr, B, 1024, 2048,
      nullptr, 1, 0);
  gconv<32,128,8,1, false,false,true, true,false><<<dim3(64,16), blk, 0, stream>>>(
      B, WH+OFF_T2, WL+OFF_T2, dect2_b, nullptr, nullptr, out, 2048, 4096,
      nullptr, 1, 0);
}

// Round 7
// 544.504 us; speedup vs baseline: 1.2629x; 1.0091x over previous
//
#include <hip/hip_runtime.h>

// ---------------------------------------------------------------------------
// VQ-VAE forward — split-fp16 MFMA everywhere.
// x = h + l*2^-11 (l prescaled by 2^11), w likewise; acc1 = h*wh,
// acc2 = h*wl + l*wh; result = acc1 + acc2/2048.  (fp32-accurate)
// Verified MFMA mapping: A[m=lane&15][k=quad*8+j] (8 consecutive k),
// B rows [n][kk] (8 consecutive kk at col n=lane&15), D col=lane&15,
// row=quad*4+reg.  kk = ci*4 + tap, tap padded to 4 with zero weights.
// R3 lesson: NEVER index register arrays with runtime values.
// R6 lesson: direct-from-global fragment gathers are TA/L1 SEGMENT-bound.
// R7 lesson: global B loads inside the barriered chunk serialize on vmcnt;
// VGPR-squeeze launch_bounds -> scratch traffic.
// R8 (kept): conv1 stages A AND B through LDS, one barrier/chunk, split-K.
// R9: fused conv+resblock+resblock into stack3_k (13 dispatches -> 9).
// R10 FIX: R9 failed absmax 7.3e-3 — intermediate halo positions OUTSIDE
// [0,1024) must be ZERO (conv "same" padding), not locally extrapolated
// (h=conv(0-pad x)+bias = bias != 0 at p<0!). HP and s0 writes now masked
// to 0 when the global position is out of range. Everything else identical.
// ---------------------------------------------------------------------------

typedef _Float16 half8 __attribute__((ext_vector_type(8)));
typedef float f32x4 __attribute__((ext_vector_type(4)));
union H8u { half8 h; int4 i; };
union P4u { _Float16 e[4]; int2 u; };

__device__ __forceinline__ void splitf(float v, _Float16& h, _Float16& l) {
  h = (_Float16)v; l = (_Float16)((v - (float)h) * 2048.0f);
}
#define INV2048 (1.0f / 2048.0f)

// ---- prepped-weight layout offsets (f16 elements) ----
#define OFF_C1   0        // conv1  [48 kkblk][32 col][64 kkin]
#define OFF_C2   98304    // conv2  [64][128]
#define OFF_C3   106496   // conv3  [64][256]
#define OFF_ER0A 122880   // enc r0 conv3 [32][256]
#define OFF_ER0B 131072   // enc r0 1x1   [64][32]
#define OFF_ER1A 133120
#define OFF_ER1B 141312
#define OFF_PQ   143360   // prevq [64][64]
#define OFF_DW1  147456   // dec conv1 [64][256]
#define OFF_DR0A 163840
#define OFF_DR0B 172032
#define OFF_DR1A 174080
#define OFF_DR1B 182272
#define OFF_T1   184320   // convT1 [64=par*32+co][256]
#define OFF_T2   200704   // convT2 [128=par*64+co][128]
#define WTOT     217088

struct WPtrs {
  const float *c1, *c2, *c3, *er0a, *er0b, *er1a, *er1b, *pq,
              *dw1, *dr0a, *dr0b, *dr1a, *dr1b, *t1, *t2;
};

__device__ __forceinline__ int tpose_kt(int par, int tap) {
  if (par == 0) { if (tap == 0) return 3; if (tap == 1) return 1; }
  else          { if (tap == 1) return 2; if (tap == 2) return 0; }
  return -1;
}

__global__ __launch_bounds__(256) void prep_k(WPtrs P, _Float16* __restrict__ WH,
                                              _Float16* __restrict__ WL) {
  int s = blockIdx.x * 256 + threadIdx.x;
  if (s >= WTOT) return;
  float v = 0.f;
  if (s < OFF_C2) {
    // conv1: [kkblk][col][kkin] (k-major blocks for contiguous LDS staging)
    int t = s, kkblk = t >> 11, rem = t & 2047, col = rem >> 6, kkin = rem & 63;
    int kk = kkblk * 64 + kkin;
    v = P.c1[col * 3072 + kk];   // == (col*768 + (kk>>2))*4 + (kk&3)
  } else if (s < OFF_C3) {
    int t = s - OFF_C2, co = t >> 7, kk = t & 127;
    v = P.c2[(co * 32 + (kk >> 2)) * 4 + (kk & 3)];
  } else if (s < OFF_ER0A) {
    int t = s - OFF_C3, co = t >> 8, kk = t & 255, tap = kk & 3;
    if (tap < 3) v = P.c3[(co * 64 + (kk >> 2)) * 3 + tap];
  } else if (s < OFF_ER0B) {
    int t = s - OFF_ER0A, co = t >> 8, kk = t & 255, tap = kk & 3;
    if (tap < 3) v = P.er0a[(co * 64 + (kk >> 2)) * 3 + tap];
  } else if (s < OFF_ER1A) {
    int t = s - OFF_ER0B; v = P.er0b[t];
  } else if (s < OFF_ER1B) {
    int t = s - OFF_ER1A, co = t >> 8, kk = t & 255, tap = kk & 3;
    if (tap < 3) v = P.er1a[(co * 64 + (kk >> 2)) * 3 + tap];
  } else if (s < OFF_PQ) {
    int t = s - OFF_ER1B; v = P.er1b[t];
  } else if (s < OFF_DW1) {
    int t = s - OFF_PQ; v = P.pq[t];
  } else if (s < OFF_DR0A) {
    int t = s - OFF_DW1, co = t >> 8, kk = t & 255, tap = kk & 3;
    if (tap < 3) v = P.dw1[(co * 64 + (kk >> 2)) * 3 + tap];
  } else if (s < OFF_DR0B) {
    int t = s - OFF_DR0A, co = t >> 8, kk = t & 255, tap = kk & 3;
    if (tap < 3) v = P.dr0a[(co * 64 + (kk >> 2)) * 3 + tap];
  } else if (s < OFF_DR1A) {
    int t = s - OFF_DR0B; v = P.dr0b[t];
  } else if (s < OFF_DR1B) {
    int t = s - OFF_DR1A, co = t >> 8, kk = t & 255, tap = kk & 3;
    if (tap < 3) v = P.dr1a[(co * 64 + (kk >> 2)) * 3 + tap];
  } else if (s < OFF_T1) {
    int t = s - OFF_DR1B; v = P.dr1b[t];
  } else if (s < OFF_T2) {
    int t = s - OFF_T1, nn = t >> 8, kk = t & 255;
    int par = nn >> 5, co = nn & 31, ci = kk >> 2;
    int kt = tpose_kt(par, kk & 3);
    if (kt >= 0) v = P.t1[(ci * 32 + co) * 4 + kt];
  } else {
    int t = s - OFF_T2, nn = t >> 7, kk = t & 127;
    int par = nn >> 6, co = nn & 63, ci = kk >> 2;
    int kt = tpose_kt(par, kk & 3);
    if (kt >= 0) v = P.t2[(ci * 64 + co) * 4 + kt];
  }
  _Float16 h, l; splitf(v, h, l);
  WH[s] = h; WL[s] = l;
}

// --------------------------- conv1 (768->32, k4 s2) -------------------------
__global__ __launch_bounds__(256, 4) void conv1_k(
    const float* __restrict__ x, const _Float16* __restrict__ WH,
    const _Float16* __restrict__ WL, float* __restrict__ Pout, int cpp) {
  __shared__ _Float16 Hs[2][16 * 136];
  __shared__ _Float16 Ls[2][16 * 136];
  __shared__ _Float16 Bhs[2][32 * 64];
  __shared__ _Float16 Bls[2][32 * 64];
  const int tid = threadIdx.x;
  const int w = tid >> 6, lane = tid & 63, lm = lane & 15, quad = lane >> 4;
  const int m0 = blockIdx.x * 64, n = blockIdx.y, kpart = blockIdx.z;
  const int r = w * 16 + lm;                  // wave-local output row 0..63
  const int pb = 2 * m0 - 1;                  // global pos of local q=0
  const float* xn = x + (size_t)n * 768 * 4096;
  const int r0s = tid / 33, c0s = tid % 33;
  const int r1s = (256 + tid) / 33, c1s = (256 + tid) % 33;
  const int r2s = (512 + tid) / 33, c2s = (512 + tid) % 33;
  const int bcol = tid >> 3, bslot = tid & 7;
  const int bdst = bcol * 64 + ((bslot ^ (bcol & 7)) << 3);

  f32x4 acc1[2], acc2[2];
#pragma unroll
  for (int j = 0; j < 2; ++j)
#pragma unroll
    for (int rr = 0; rr < 4; ++rr) { acc1[j][rr] = 0.f; acc2[j][rr] = 0.f; }

  const int cb0 = kpart * cpp;
  float4 sv0, sv1, sv2;
  H8u bhv, blv;

#define C1_LD1(SV, RS, CS) { \
    int p0 = pb + 4 * (CS); \
    const float* rp = xn + (size_t)(chb + (RS)) * 4096; \
    if (p0 >= 0 && p0 + 3 < 4096) SV = *(const float4*)(rp + p0); \
    else { \
      SV.x = (p0   >= 0 && p0   < 4096) ? rp[p0]   : 0.f; \
      SV.y = (p0+1 >= 0 && p0+1 < 4096) ? rp[p0+1] : 0.f; \
      SV.z = (p0+2 >= 0 && p0+2 < 4096) ? rp[p0+2] : 0.f; \
      SV.w = (p0+3 >= 0 && p0+3 < 4096) ? rp[p0+3] : 0.f; } }

#define C1_LOAD(cc) { \
    int chb = (cb0 + (cc)) * 16; \
    C1_LD1(sv0, r0s, c0s) \
    C1_LD1(sv1, r1s, c1s) \
    if (tid < 16) C1_LD1(sv2, r2s, c2s) \
    bhv.i = *(const int4*)(WH + (size_t)(cb0 + (cc)) * 2048 + tid * 8); \
    blv.i = *(const int4*)(WL + (size_t)(cb0 + (cc)) * 2048 + tid * 8); }

#define C1_WR1(SV, RS, CS, B) { \
    P4u ph, pl; \
    splitf(SV.x, ph.e[0], pl.e[0]); splitf(SV.y, ph.e[1], pl.e[1]); \
    splitf(SV.z, ph.e[2], pl.e[2]); splitf(SV.w, ph.e[3], pl.e[3]); \
    *(int2*)(&Hs[B][(RS) * 136 + 4 * (CS)]) = ph.u; \
    *(int2*)(&Ls[B][(RS) * 136 + 4 * (CS)]) = pl.u; }

#define C1_WRITE(B) { \
    C1_WR1(sv0, r0s, c0s, B) \
    C1_WR1(sv1, r1s, c1s, B) \
    if (tid < 16) C1_WR1(sv2, r2s, c2s, B) \
    *(int4*)(&Bhs[B][bdst]) = bhv.i; \
    *(int4*)(&Bls[B][bdst]) = blv.i; }

#define C1_COMP(B) { \
    const uint* Hdw = (const uint*)(&Hs[B][0]); \
    const uint* Ldw = (const uint*)(&Ls[B][0]); \
    _Pragma("unroll") \
    for (int ks = 0; ks < 2; ++ks) { \
      const int ci0 = ks * 8 + quad * 2; \
      const int bse = ci0 * 68 + r; \
      H8u ah, al; \
      ah.i.x = Hdw[bse];      ah.i.y = Hdw[bse + 1]; \
      ah.i.z = Hdw[bse + 68]; ah.i.w = Hdw[bse + 69]; \
      al.i.x = Ldw[bse];      al.i.y = Ldw[bse + 1]; \
      al.i.z = Ldw[bse + 68]; al.i.w = Ldw[bse + 69]; \
      const int sA = ((4 * ks + quad) ^ (lm & 7)) << 3; \
      H8u b0h, b0l, b1h, b1l; \
      b0h.i = *(const int4*)(&Bhs[B][lm * 64 + sA]); \
      b0l.i = *(const int4*)(&Bls[B][lm * 64 + sA]); \
      b1h.i = *(const int4*)(&Bhs[B][(16 + lm) * 64 + sA]); \
      b1l.i = *(const int4*)(&Bls[B][(16 + lm) * 64 + sA]); \
      acc1[0] = __builtin_amdgcn_mfma_f32_16x16x32_f16(ah.h, b0h.h, acc1[0], 0,0,0); \
      acc2[0] = __builtin_amdgcn_mfma_f32_16x16x32_f16(ah.h, b0l.h, acc2[0], 0,0,0); \
      acc2[0] = __builtin_amdgcn_mfma_f32_16x16x32_f16(al.h, b0h.h, acc2[0], 0,0,0); \
      acc1[1] = __builtin_amdgcn_mfma_f32_16x16x32_f16(ah.h, b1h.h, acc1[1], 0,0,0); \
      acc2[1] = __builtin_amdgcn_mfma_f32_16x16x32_f16(ah.h, b1l.h, acc2[1], 0,0,0); \
      acc2[1] = __builtin_amdgcn_mfma_f32_16x16x32_f16(al.h, b1h.h, acc2[1], 0,0,0); \
    } }

  C1_LOAD(0);
  C1_WRITE(0);
  __syncthreads();
#pragma unroll 1
  for (int cc = 0; cc < cpp; ++cc) {
    const int cur = cc & 1;
    if (cc + 1 < cpp) C1_LOAD(cc + 1);
    C1_COMP(cur);
    if (cc + 1 < cpp) C1_WRITE(cur ^ 1);
    __syncthreads();
  }

#pragma unroll
  for (int j = 0; j < 2; ++j) {
    int col = j * 16 + lm;
    float4 o;
    o.x = acc1[j][0] + acc2[j][0] * INV2048;
    o.y = acc1[j][1] + acc2[j][1] * INV2048;
    o.z = acc1[j][2] + acc2[j][2] * INV2048;
    o.w = acc1[j][3] + acc2[j][3] * INV2048;
    *(float4*)(Pout + (size_t)kpart * (16 * 32 * 2048)
               + ((size_t)n * 32 + col) * 2048 + m0 + w * 16 + quad * 4) = o;
  }
#undef C1_LD1
#undef C1_LOAD
#undef C1_WR1
#undef C1_WRITE
#undef C1_COMP
}

// ---------------- k3 MFMA helper (KP=256, 8 ks, B prefetched) ---------------
template<int NTW_>
__device__ __forceinline__ void k3_mfma(
    const _Float16* __restrict__ AGH, const _Float16* __restrict__ AGL,
    int arow, const _Float16* __restrict__ WHp, const _Float16* __restrict__ WLp,
    int colb, int lm, int quad, f32x4 (&a1)[NTW_], f32x4 (&a2)[NTW_]) {
  H8u bh[2][NTW_], bl[2][NTW_];
#pragma unroll
  for (int j = 0; j < NTW_; ++j) {
    int col = colb + j * 16 + lm;
    bh[0][j].i = *(const int4*)(WHp + (size_t)col * 256 + quad * 8);
    bl[0][j].i = *(const int4*)(WLp + (size_t)col * 256 + quad * 8);
  }
#pragma unroll
  for (int ks = 0; ks < 8; ++ks) {
    int cur = ks & 1;
    if (ks + 1 < 8) {
#pragma unroll
      for (int j = 0; j < NTW_; ++j) {
        int col = colb + j * 16 + lm;
        bh[cur ^ 1][j].i = *(const int4*)(WHp + (size_t)col * 256 + (ks+1) * 32 + quad * 8);
        bl[cur ^ 1][j].i = *(const int4*)(WLp + (size_t)col * 256 + (ks+1) * 32 + quad * 8);
      }
    }
    H8u ah, al;
    ah.i = *(const int4*)(&AGH[(arow + lm) * 264 + ks * 32 + quad * 8]);
    al.i = *(const int4*)(&AGL[(arow + lm) * 264 + ks * 32 + quad * 8]);
#pragma unroll
    for (int j = 0; j < NTW_; ++j) {
      a1[j] = __builtin_amdgcn_mfma_f32_16x16x32_f16(ah.h, bh[cur][j].h, a1[j], 0,0,0);
      a2[j] = __builtin_amdgcn_mfma_f32_16x16x32_f16(ah.h, bl[cur][j].h, a2[j], 0,0,0);
      a2[j] = __builtin_amdgcn_mfma_f32_16x16x32_f16(al.h, bh[cur][j].h, a2[j], 0,0,0);
    }
  }
}

// ---------- fused conv(k3,bias) + resblock + resblock (64ch, L=1024) --------
// Per block: M-tile 32 final outputs at [m0, m0+32). Chain with halos:
//   x staged [m0-17, m0+49) (stride 68, zero-padded outside [0,1024))
//   h = conv(x)+bias on [m0-16, m0+48) — MASKED to 0 outside [0,1024)!
//   r0a = c3(relu h) on [m0-8, m0+40) (48 pos) -> RP raw
//   s0  = h + 1x1(relu r0a) on same 48 pos — MASKED to 0 outside [0,1024)!
//   r1a = c3(relu s0) on [m0, m0+32) -> RP raw
//   out = s0 + 1x1(relu r1a), stored raw (consumer applies final relu)
// The masks reproduce conv "same" zero-padding of the unfused chain (R10).
__global__ __launch_bounds__(256, 2) void stack3_k(
    const float* __restrict__ in,
    const _Float16* __restrict__ WAH, const _Float16* __restrict__ WAL,
    const float* __restrict__ biasA,
    const _Float16* __restrict__ W0AH, const _Float16* __restrict__ W0AL,
    const _Float16* __restrict__ W0BH, const _Float16* __restrict__ W0BL,
    const _Float16* __restrict__ W1AH, const _Float16* __restrict__ W1AL,
    const _Float16* __restrict__ W1BH, const _Float16* __restrict__ W1BL,
    float* __restrict__ out) {
  __shared__ float XS[64 * 68];        // x (stride 68) -> reused as s0 (stride 52)
  __shared__ float HP[64 * 68];        // h plane (stride 68, 64 used)
  __shared__ float RP[32 * 52];        // r0a out (48 rows) -> reused r1a out (32)
  __shared__ _Float16 AGH[32 * 264];   // k3 A-gather high; also A2 [48*40]
  __shared__ _Float16 AGL[32 * 264];
  const int tid = threadIdx.x;
  const int w = tid >> 6, lane = tid & 63, lm = lane & 15, quad = lane >> 4;
  const int m0 = blockIdx.x * 32, n = blockIdx.y;
  const float* inN = in + (size_t)n * 64 * 1024;

  // ---- stage x: 68 slots of q, q = p - (m0-17) ----
  {
    const int pb = m0 - 17;
#pragma unroll
    for (int it = 0; it < 5; ++it) {
      int idx = it * 256 + tid;
      if (idx < 64 * 17) {
        int row = idx / 17, c4 = idx % 17;
        int p0 = pb + c4 * 4;
        const float* rp = inN + (size_t)row * 1024;
        float4 v;
        if (p0 >= 0 && p0 + 3 < 1024) v = *(const float4*)(rp + p0);
        else {
          v.x = (p0   >= 0 && p0   < 1024) ? rp[p0]   : 0.f;
          v.y = (p0+1 >= 0 && p0+1 < 1024) ? rp[p0+1] : 0.f;
          v.z = (p0+2 >= 0 && p0+2 < 1024) ? rp[p0+2] : 0.f;
          v.w = (p0+3 >= 0 && p0+3 < 1024) ? rp[p0+3] : 0.f;
        }
        *(float4*)(&XS[row * 68 + c4 * 4]) = v;
      }
    }
  }
  __syncthreads();

#define GATH64(SRC, SSTR, OFS, ROWS, RELUF) { \
    _Pragma("unroll") \
    for (int it = 0; it < (ROWS) / 4; ++it) { \
      int slot = it * 256 + tid; \
      int ci = slot & 63, m = slot >> 6; \
      const float* xr = &SRC[ci * (SSTR) + (OFS) + m]; \
      float a0 = xr[0], a1v = xr[1], a2v = xr[2], a3 = xr[3]; \
      if (RELUF) { a0 = fmaxf(a0,0.f); a1v = fmaxf(a1v,0.f); \
                   a2v = fmaxf(a2v,0.f); a3 = fmaxf(a3,0.f); } \
      P4u ph, pl; \
      splitf(a0, ph.e[0], pl.e[0]); splitf(a1v, ph.e[1], pl.e[1]); \
      splitf(a2v, ph.e[2], pl.e[2]); splitf(a3, ph.e[3], pl.e[3]); \
      *(int2*)(&AGH[m * 264 + ci * 4]) = ph.u; \
      *(int2*)(&AGL[m * 264 + ci * 4]) = pl.u; } }

  // ---- conv A: h on 64 positions, 2 passes of 32 (masked outside [0,1024)) --
#pragma unroll
  for (int P = 0; P < 2; ++P) {
    GATH64(XS, 68, P * 32, 32, false);
    __syncthreads();
    {
      f32x4 a1[2], a2[2];
#pragma unroll
      for (int j = 0; j < 2; ++j)
#pragma unroll
        for (int rr = 0; rr < 4; ++rr) { a1[j][rr] = 0.f; a2[j][rr] = 0.f; }
      k3_mfma<2>(AGH, AGL, (w >> 1) * 16, WAH, WAL, (w & 1) * 32, lm, quad, a1, a2);
#pragma unroll
      for (int j = 0; j < 2; ++j) {
        int col = (w & 1) * 32 + j * 16 + lm;
        float bv = biasA[col];
#pragma unroll
        for (int rr = 0; rr < 4; ++rr) {
          int m = (w >> 1) * 16 + quad * 4 + rr;
          int qh = P * 32 + m;                 // h-plane local index
          int gp = m0 - 16 + qh;               // global position
          float hv = a1[j][rr] + a2[j][rr] * INV2048 + bv;
          HP[col * 68 + qh] = (gp >= 0 && gp < 1024) ? hv : 0.f;
        }
      }
    }
    __syncthreads();
  }

  // ---- r0a: c3(relu h) on 48 positions (pass0: 32 rows, pass1: 16) ----
  GATH64(HP, 68, 7, 32, true);
  __syncthreads();
  {
    f32x4 a1[1], a2[1];
#pragma unroll
    for (int rr = 0; rr < 4; ++rr) { a1[0][rr] = 0.f; a2[0][rr] = 0.f; }
    k3_mfma<1>(AGH, AGL, (w >> 1) * 16, W0AH, W0AL, (w & 1) * 16, lm, quad, a1, a2);
    int col2 = (w & 1) * 16 + lm;
#pragma unroll
    for (int rr = 0; rr < 4; ++rr) {
      int m = (w >> 1) * 16 + quad * 4 + rr;
      RP[col2 * 52 + m] = a1[0][rr] + a2[0][rr] * INV2048;
    }
  }
  __syncthreads();
  GATH64(HP, 68, 39, 16, true);
  __syncthreads();
  if ((w >> 1) == 0) {
    f32x4 a1[1], a2[1];
#pragma unroll
    for (int rr = 0; rr < 4; ++rr) { a1[0][rr] = 0.f; a2[0][rr] = 0.f; }
    k3_mfma<1>(AGH, AGL, 0, W0AH, W0AL, (w & 1) * 16, lm, quad, a1, a2);
    int col2 = (w & 1) * 16 + lm;
#pragma unroll
    for (int rr = 0; rr < 4; ++rr) {
      int m = quad * 4 + rr;
      RP[col2 * 52 + 32 + m] = a1[0][rr] + a2[0][rr] * INV2048;
    }
  }
  __syncthreads();

  // ---- r0b: s0 = h + 1x1(relu r0a) on 48 positions -> XS (stride 52),
  //      masked to 0 outside [0,1024) ----
#pragma unroll
  for (int it = 0; it < 6; ++it) {
    int slot = it * 256 + tid;
    int ci = slot & 31, m = slot >> 5;
    float v = fmaxf(RP[ci * 52 + m], 0.f);
    _Float16 h, l; splitf(v, h, l);
    AGH[m * 40 + ci] = h; AGL[m * 40 + ci] = l;
  }
  __syncthreads();
  {
    int col = w * 16 + lm;
    H8u wbh, wbl;
    wbh.i = *(const int4*)(W0BH + col * 32 + quad * 8);
    wbl.i = *(const int4*)(W0BL + col * 32 + quad * 8);
#pragma unroll
    for (int mt2 = 0; mt2 < 3; ++mt2) {
      f32x4 c1 = {0.f,0.f,0.f,0.f}, c2 = {0.f,0.f,0.f,0.f};
      H8u a2h, a2l;
      a2h.i = *(const int4*)(&AGH[(mt2 * 16 + lm) * 40 + quad * 8]);
      a2l.i = *(const int4*)(&AGL[(mt2 * 16 + lm) * 40 + quad * 8]);
      c1 = __builtin_amdgcn_mfma_f32_16x16x32_f16(a2h.h, wbh.h, c1, 0,0,0);
      c2 = __builtin_amdgcn_mfma_f32_16x16x32_f16(a2h.h, wbl.h, c2, 0,0,0);
      c2 = __builtin_amdgcn_mfma_f32_16x16x32_f16(a2l.h, wbh.h, c2, 0,0,0);
#pragma unroll
      for (int rr = 0; rr < 4; ++rr) {
        int qs = mt2 * 16 + quad * 4 + rr;
        int gp = m0 - 8 + qs;                  // global position of s0 slot
        float sv = HP[col * 68 + qs + 8] + c1[rr] + c2[rr] * INV2048;
        XS[col * 52 + qs] = (gp >= 0 && gp < 1024) ? sv : 0.f;
      }
    }
  }
  __syncthreads();

  // ---- r1a: c3(relu s0) on 32 positions -> RP raw ----
  GATH64(XS, 52, 7, 32, true);
  __syncthreads();
  {
    f32x4 a1[1], a2[1];
#pragma unroll
    for (int rr = 0; rr < 4; ++rr) { a1[0][rr] = 0.f; a2[0][rr] = 0.f; }
    k3_mfma<1>(AGH, AGL, (w >> 1) * 16, W1AH, W1AL, (w & 1) * 16, lm, quad, a1, a2);
    int col2 = (w & 1) * 16 + lm;
#pragma unroll
    for (int rr = 0; rr < 4; ++rr) {
      int m = (w >> 1) * 16 + quad * 4 + rr;
      RP[col2 * 52 + m] = a1[0][rr] + a2[0][rr] * INV2048;
    }
  }
  __syncthreads();

  // ---- r1b: out = s0 + 1x1(relu r1a), store raw ----
#pragma unroll
  for (int it = 0; it < 4; ++it) {
    int slot = it * 256 + tid;
    int ci = slot & 31, m = slot >> 5;
    float v = fmaxf(RP[ci * 52 + m], 0.f);
    _Float16 h, l; splitf(v, h, l);
    AGH[m * 40 + ci] = h; AGL[m * 40 + ci] = l;
  }
  __syncthreads();
  {
    int mt2 = w >> 1, ntb2 = (w & 1) * 2;
    H8u a2h, a2l;
    a2h.i = *(const int4*)(&AGH[(mt2 * 16 + lm) * 40 + quad * 8]);
    a2l.i = *(const int4*)(&AGL[(mt2 * 16 + lm) * 40 + quad * 8]);
#pragma unroll
    for (int j = 0; j < 2; ++j) {
      int col = (ntb2 + j) * 16 + lm;
      H8u wbh, wbl;
      wbh.i = *(const int4*)(W1BH + col * 32 + quad * 8);
      wbl.i = *(const int4*)(W1BL + col * 32 + quad * 8);
      f32x4 c1 = {0.f,0.f,0.f,0.f}, c2 = {0.f,0.f,0.f,0.f};
      c1 = __builtin_amdgcn_mfma_f32_16x16x32_f16(a2h.h, wbh.h, c1, 0,0,0);
      c2 = __builtin_amdgcn_mfma_f32_16x16x32_f16(a2h.h, wbl.h, c2, 0,0,0);
      c2 = __builtin_amdgcn_mfma_f32_16x16x32_f16(a2l.h, wbh.h, c2, 0,0,0);
      float4 o;
#pragma unroll
      for (int rr = 0; rr < 4; ++rr) {
        int m = mt2 * 16 + quad * 4 + rr;
        ((float*)&o)[rr] = XS[col * 52 + m + 8] + c1[rr] + c2[rr] * INV2048;
      }
      *(float4*)(out + ((size_t)n * 64 + col) * 1024 + m0 + mt2 * 16 + quad * 4) = o;
    }
  }
#undef GATH64
}

// ------------------- generic one-shot MFMA conv (M-tile 32) -----------------
template<int CI, int KP, int NT, int STRIDE,
         bool RELU_IN, bool RELU_OUT, bool BIAS, bool TPOSE, bool RESBLK,
         bool PSUM = false>
__global__ __launch_bounds__(256) void gconv(
    const float* __restrict__ in, const _Float16* __restrict__ WH,
    const _Float16* __restrict__ WL, const float* __restrict__ bias,
    const _Float16* __restrict__ W2H, const _Float16* __restrict__ W2L,
    float* __restrict__ out, int Lin, int Lout,
    const float* __restrict__ inbias, int nparts, int pplane) {
  constexpr int CP = 32 * STRIDE + 4;
  constexpr int CP4 = CP / 4;
  constexpr int AP = KP + 8;
  constexpr int KS = KP / 32;
  constexpr int NTW = (NT == 2) ? 1 : NT / 2;
  __shared__ float xs[CI * CP];
  __shared__ _Float16 Ah[32 * AP];
  __shared__ _Float16 Al[32 * AP];
  __shared__ _Float16 A2h[RESBLK ? 32 * 40 : 1];
  __shared__ _Float16 A2l[RESBLK ? 32 * 40 : 1];
  const int tid = threadIdx.x;
  const int w = tid >> 6, lane = tid & 63, lm = lane & 15, quad = lane >> 4;
  const int mt = w >> 1, ntb = (w & 1) * NTW;
  const int m0 = blockIdx.x * 32, n = blockIdx.y;
  const int base = m0 * STRIDE - 1;
  const float* inN = in + (size_t)n * CI * Lin;
  constexpr int SLOTS = CI * CP4;
#pragma unroll
  for (int it = 0; it < (SLOTS + 255) / 256; ++it) {
    int idx = it * 256 + tid;
    if (idx < SLOTS) {
      int row = idx / CP4, c4 = idx % CP4;
      int p0 = base + c4 * 4;
      const float* rp = inN + (size_t)row * Lin;
      float4 v;
      if (PSUM) {
        v.x = 0.f; v.y = 0.f; v.z = 0.f; v.w = 0.f;
        bool i0 = (p0   >= 0 && p0   < Lin);
        bool i1 = (p0+1 >= 0 && p0+1 < Lin);
        bool i2 = (p0+2 >= 0 && p0+2 < Lin);
        bool i3 = (p0+3 >= 0 && p0+3 < Lin);
        bool full = (p0 >= 0 && p0 + 3 < Lin);
        for (int p = 0; p < nparts; ++p) {
          const float* rpp = rp + (size_t)p * pplane;
          if (full) {
            float4 t = *(const float4*)(rpp + p0);
            v.x += t.x; v.y += t.y; v.z += t.z; v.w += t.w;
          } else {
            if (i0) v.x += rpp[p0];
            if (i1) v.y += rpp[p0+1];
            if (i2) v.z += rpp[p0+2];
            if (i3) v.w += rpp[p0+3];
          }
        }
        float bv = inbias[row];
        v.x = i0 ? fmaxf(v.x + bv, 0.f) : 0.f;
        v.y = i1 ? fmaxf(v.y + bv, 0.f) : 0.f;
        v.z = i2 ? fmaxf(v.z + bv, 0.f) : 0.f;
        v.w = i3 ? fmaxf(v.w + bv, 0.f) : 0.f;
      } else {
        if (p0 >= 0 && p0 + 3 < Lin) v = *(const float4*)(rp + p0);
        else {
          v.x = (p0   >= 0 && p0   < Lin) ? rp[p0]   : 0.f;
          v.y = (p0+1 >= 0 && p0+1 < Lin) ? rp[p0+1] : 0.f;
          v.z = (p0+2 >= 0 && p0+2 < Lin) ? rp[p0+2] : 0.f;
          v.w = (p0+3 >= 0 && p0+3 < Lin) ? rp[p0+3] : 0.f;
        }
      }
      *(float4*)(&xs[row * CP + c4 * 4]) = v;
    }
  }
  __syncthreads();
#pragma unroll
  for (int it = 0; it < (32 * CI) / 256; ++it) {
    int slot = it * 256 + tid;
    int ci = slot & (CI - 1), m = slot / CI;
    const float* xr = &xs[ci * CP + STRIDE * m];
    float a0 = xr[0], a1 = xr[1], a2 = xr[2], a3 = xr[3];
    if (RELU_IN) { a0 = fmaxf(a0,0.f); a1 = fmaxf(a1,0.f);
                   a2 = fmaxf(a2,0.f); a3 = fmaxf(a3,0.f); }
    P4u ph, pl;
    splitf(a0, ph.e[0], pl.e[0]); splitf(a1, ph.e[1], pl.e[1]);
    splitf(a2, ph.e[2], pl.e[2]); splitf(a3, ph.e[3], pl.e[3]);
    *(int2*)(&Ah[m * AP + ci * 4]) = ph.u;
    *(int2*)(&Al[m * AP + ci * 4]) = pl.u;
  }
  __syncthreads();
  f32x4 acc1[NTW], acc2[NTW];
#pragma unroll
  for (int j = 0; j < NTW; ++j)
#pragma unroll
    for (int r = 0; r < 4; ++r) { acc1[j][r] = 0.f; acc2[j][r] = 0.f; }
  H8u bh[2][NTW], bl[2][NTW];
#pragma unroll
  for (int j = 0; j < NTW; ++j) {
    int col = (ntb + j) * 16 + lm;
    bh[0][j].i = *(const int4*)(WH + (size_t)col * KP + quad * 8);
    bl[0][j].i = *(const int4*)(WL + (size_t)col * KP + quad * 8);
  }
#pragma unroll
  for (int ks = 0; ks < KS; ++ks) {
    int cur = ks & 1;
    if (ks + 1 < KS) {
#pragma unroll
      for (int j = 0; j < NTW; ++j) {
        int col = (ntb + j) * 16 + lm;
        bh[cur ^ 1][j].i = *(const int4*)(WH + (size_t)col * KP + (ks+1) * 32 + quad * 8);
        bl[cur ^ 1][j].i = *(const int4*)(WL + (size_t)col * KP + (ks+1) * 32 + quad * 8);
      }
    }
    H8u ah, al;
    ah.i = *(const int4*)(&Ah[(mt * 16 + lm) * AP + ks * 32 + quad * 8]);
    al.i = *(const int4*)(&Al[(mt * 16 + lm) * AP + ks * 32 + quad * 8]);
#pragma unroll
    for (int j = 0; j < NTW; ++j) {
      acc1[j] = __builtin_amdgcn_mfma_f32_16x16x32_f16(ah.h, bh[cur][j].h, acc1[j], 0,0,0);
      acc2[j] = __builtin_amdgcn_mfma_f32_16x16x32_f16(ah.h, bl[cur][j].h, acc2[j], 0,0,0);
      acc2[j] = __builtin_amdgcn_mfma_f32_16x16x32_f16(al.h, bh[cur][j].h, acc2[j], 0,0,0);
    }
  }
  if (RESBLK) {
    int co2 = (w & 1) * 16 + lm;
#pragma unroll
    for (int r = 0; r < 4; ++r) {
      float hv = fmaxf(acc1[0][r] + acc2[0][r] * INV2048, 0.f);
      _Float16 hh, hl; splitf(hv, hh, hl);
      int m = mt * 16 + quad * 4 + r;
      A2h[m * 40 + co2] = hh; A2l[m * 40 + co2] = hl;
    }
    __syncthreads();
    f32x4 c1[2], c2[2];
#pragma unroll
    for (int j = 0; j < 2; ++j)
#pragma unroll
      for (int r = 0; r < 4; ++r) { c1[j][r] = 0.f; c2[j][r] = 0.f; }
    H8u a2h, a2l;
    a2h.i = *(const int4*)(&A2h[(mt * 16 + lm) * 40 + quad * 8]);
    a2l.i = *(const int4*)(&A2l[(mt * 16 + lm) * 40 + quad * 8]);
    int ntb2 = (w & 1) * 2;
#pragma unroll
    for (int j = 0; j < 2; ++j) {
      int col = (ntb2 + j) * 16 + lm;
      H8u wbh, wbl;
      wbh.i = *(const int4*)(W2H + col * 32 + quad * 8);
      wbl.i = *(const int4*)(W2L + col * 32 + quad * 8);
      c1[j] = __builtin_amdgcn_mfma_f32_16x16x32_f16(a2h.h, wbh.h, c1[j], 0,0,0);
      c2[j] = __builtin_amdgcn_mfma_f32_16x16x32_f16(a2h.h, wbl.h, c2[j], 0,0,0);
      c2[j] = __builtin_amdgcn_mfma_f32_16x16x32_f16(a2l.h, wbh.h, c2[j], 0,0,0);
    }
#pragma unroll
    for (int j = 0; j < 2; ++j) {
      int col = (ntb2 + j) * 16 + lm;
      float4 o;
#pragma unroll
      for (int r = 0; r < 4; ++r) {
        int m = mt * 16 + quad * 4 + r;
        float res = xs[col * CP + m + 1];
        ((float*)&o)[r] = res + c1[j][r] + c2[j][r] * INV2048;
      }
      *(float4*)(out + ((size_t)n * 64 + col) * Lout + m0 + mt * 16 + quad * 4) = o;
    }
  } else {
    constexpr int CO = TPOSE ? NT * 8 : NT * 16;
#pragma unroll
    for (int j = 0; j < NTW; ++j) {
      int col = (ntb + j) * 16 + lm;
      int par = TPOSE ? (col / CO) : 0;
      int co  = TPOSE ? (col % CO) : col;
      float bv = BIAS ? bias[co] : 0.f;
      float vr[4];
#pragma unroll
      for (int r = 0; r < 4; ++r) {
        float v = acc1[j][r] + acc2[j][r] * INV2048 + bv;
        vr[r] = RELU_OUT ? fmaxf(v, 0.f) : v;
      }
      if (TPOSE) {
#pragma unroll
        for (int r = 0; r < 4; ++r) {
          int m = m0 + mt * 16 + quad * 4 + r;
          out[((size_t)n * CO + co) * Lout + 2 * m + par] = vr[r];
        }
      } else {
        float4 o; o.x = vr[0]; o.y = vr[1]; o.z = vr[2]; o.w = vr[3];
        *(float4*)(out + ((size_t)n * CO + co) * Lout + m0 + mt * 16 + quad * 4) = o;
      }
    }
  }
}

// ------------------------------ codebook norms ------------------------------
__global__ void enorm_k(const float* __restrict__ emb, float* __restrict__ en) {
  int e = blockIdx.x * blockDim.x + threadIdx.x;
  if (e >= 512) return;
  float s = 0.f;
  const float* r = emb + (size_t)e * 64;
  for (int c = 0; c < 64; ++c) s = fmaf(r[c], r[c], s);
  en[e] = s;
}

// ------------------ fused prevq (1x1, relu-in) + VQ -------------------------
__global__ __launch_bounds__(256) void vq_fused(
    const float* __restrict__ sIn, const _Float16* __restrict__ PQH,
    const _Float16* __restrict__ PQL, const float* __restrict__ pqb,
    const float* __restrict__ emb, const float* __restrict__ en,
    float* __restrict__ q) {
  __shared__ float xs[64 * 68];
  __shared__ _Float16 Ah[64 * 72];
  __shared__ _Float16 Al[64 * 72];
  __shared__ float zl[64 * 65];
  __shared__ float dred[4 * 64];
  __shared__ int   ired[4 * 64];
  __shared__ int   idxs[64];
  const int tid = threadIdx.x;
  const int w = tid >> 6, lane = tid & 63, lm = lane & 15, quad = lane >> 4;
  const int n = blockIdx.y, t0 = blockIdx.x * 64;
#pragma unroll
  for (int it = 0; it < 4; ++it) {
    int idx = it * 256 + tid;
    int row = idx >> 4, c4 = idx & 15;
    float4 v = *(const float4*)(sIn + ((size_t)n * 64 + row) * 1024 + t0 + c4 * 4);
    *(float4*)(&xs[row * 68 + c4 * 4]) = v;
  }
  __syncthreads();
#pragma unroll
  for (int it = 0; it < 16; ++it) {
    int slot = it * 256 + tid;
    int ci = slot & 63, t = slot >> 6;
    float v = fmaxf(xs[ci * 68 + t], 0.f);
    _Float16 h, l; splitf(v, h, l);
    Ah[t * 72 + ci] = h; Al[t * 72 + ci] = l;
  }
  __syncthreads();
  f32x4 a1[4], a2[4];
#pragma unroll
  for (int j = 0; j < 4; ++j)
#pragma unroll
    for (int r = 0; r < 4; ++r) { a1[j][r] = 0.f; a2[j][r] = 0.f; }
#pragma unroll
  for (int ks = 0; ks < 2; ++ks) {
    H8u ah, al;
    ah.i = *(const int4*)(&Ah[(w * 16 + lm) * 72 + ks * 32 + quad * 8]);
    al.i = *(const int4*)(&Al[(w * 16 + lm) * 72 + ks * 32 + quad * 8]);
#pragma unroll
    for (int j = 0; j < 4; ++j) {
      int col = j * 16 + lm;
      H8u bh, bl;
      bh.i = *(const int4*)(PQH + col * 64 + ks * 32 + quad * 8);
      bl.i = *(const int4*)(PQL + col * 64 + ks * 32 + quad * 8);
      a1[j] = __builtin_amdgcn_mfma_f32_16x16x32_f16(ah.h, bh.h, a1[j], 0,0,0);
      a2[j] = __builtin_amdgcn_mfma_f32_16x16x32_f16(ah.h, bl.h, a2[j], 0,0,0);
      a2[j] = __builtin_amdgcn_mfma_f32_16x16x32_f16(al.h, bh.h, a2[j], 0,0,0);
    }
  }
#pragma unroll
  for (int j = 0; j < 4; ++j) {
    int col = j * 16 + lm;
    float bv = pqb[col];
#pragma unroll
    for (int r = 0; r < 4; ++r) {
      int t = w * 16 + quad * 4 + r;
      zl[t * 65 + col] = a1[j][r] + a2[j][r] * INV2048 + bv;
    }
  }
  __syncthreads();
  int tt = tid & 63, cq = tid >> 6;
  float zv[64];
#pragma unroll
  for (int c = 0; c < 64; ++c) zv[c] = zl[tt * 65 + c];
  float best = 1e30f; int bidx = 0;
  for (int e = cq * 128; e < cq * 128 + 128; ++e) {
    const float* er = emb + (size_t)e * 64;
    float dot = 0.f;
#pragma unroll
    for (int c = 0; c < 64; ++c) dot = fmaf(zv[c], er[c], dot);
    float d = en[e] - 2.f * dot;
    if (d < best) { best = d; bidx = e; }
  }
  dred[cq * 64 + tt] = best;
  ired[cq * 64 + tt] = bidx;
  __syncthreads();
  if (cq == 0) {
    for (int j = 1; j < 4; ++j) {
      float d = dred[j * 64 + tt]; int i2 = ired[j * 64 + tt];
      if (d < best || (d == best && i2 < bidx)) { best = d; bidx = i2; }
    }
    idxs[tt] = bidx;
  }
  __syncthreads();
  for (int it = 0; it < 16; ++it) {
    int c = cq * 16 + it;
    q[((size_t)n * 64 + c) * 1024 + t0 + tt] = emb[(size_t)idxs[tt] * 64 + c];
  }
}

// ---------------------------------------------------------------------------
extern "C" void kernel_launch(void* const* d_in, const int* in_sizes, int n_in,
                              void* d_out, int out_size, void* d_ws, size_t ws_size,
                              hipStream_t stream) {
  const float* x        = (const float*)d_in[0];
  const float* enc_b1   = (const float*)d_in[2];
  const float* enc_b2   = (const float*)d_in[4];
  const float* enc_b3   = (const float*)d_in[6];
  const float* prevq_b  = (const float*)d_in[12];
  const float* emb      = (const float*)d_in[13];
  const float* dec_b1   = (const float*)d_in[15];
  const float* dect1_b  = (const float*)d_in[21];
  const float* dect2_b  = (const float*)d_in[23];
  float* out = (float*)d_out;

  WPtrs P;
  P.c1  = (const float*)d_in[1];  P.c2  = (const float*)d_in[3];
  P.c3  = (const float*)d_in[5];  P.er0a = (const float*)d_in[7];
  P.er0b = (const float*)d_in[8]; P.er1a = (const float*)d_in[9];
  P.er1b = (const float*)d_in[10]; P.pq = (const float*)d_in[11];
  P.dw1 = (const float*)d_in[14]; P.dr0a = (const float*)d_in[16];
  P.dr0b = (const float*)d_in[17]; P.dr1a = (const float*)d_in[18];
  P.dr1b = (const float*)d_in[19]; P.t1 = (const float*)d_in[20];
  P.t2  = (const float*)d_in[22];

  float* A  = (float*)d_ws;                   // 1M floats
  float* B  = A + (1u << 20);                 // 1M floats
  float* EN = B + (1u << 20);                 // 512 floats
  _Float16* WH = (_Float16*)(EN + 1024);      // WTOT f16
  _Float16* WL = WH + WTOT;
  float* PP = (float*)(WL + WTOT);            // conv1 split-K partial planes

  const size_t baseBytes = (size_t)((char*)PP - (char*)d_ws);
  const size_t planeB = (size_t)16 * 32 * 2048 * 4;
  int nparts = 1;
  float* Pbuf = A;                            // nparts==1: reuse A directly
  if (ws_size >= baseBytes + 2 * planeB) { nparts = 2; Pbuf = PP; }

  dim3 blk(256);
  prep_k<<<dim3((WTOT + 255) / 256), blk, 0, stream>>>(P, WH, WL);
  enorm_k<<<dim3(2), blk, 0, stream>>>(emb, EN);
  // encoder — conv1 writes raw split-K partials; conv2 sums + bias + relu
  conv1_k<<<dim3(32, 16, nparts), blk, 0, stream>>>(x, WH + OFF_C1, WL + OFF_C1,
                                                    Pbuf, 48 / nparts);
  gconv<32,128,4,2, false,true,true, false,false, true><<<dim3(32,16), blk, 0, stream>>>(
      Pbuf, WH+OFF_C2, WL+OFF_C2, enc_b2, nullptr, nullptr, B, 2048, 1024,
      enc_b1, nparts, 16 * 32 * 2048);
  // fused conv3 + resblock x2 (encoder)
  stack3_k<<<dim3(32,16), blk, 0, stream>>>(
      B, WH+OFF_C3, WL+OFF_C3, enc_b3,
      WH+OFF_ER0A, WL+OFF_ER0A, WH+OFF_ER0B, WL+OFF_ER0B,
      WH+OFF_ER1A, WL+OFF_ER1A, WH+OFF_ER1B, WL+OFF_ER1B, A);
  // VQ (prevq + relu fused)
  vq_fused<<<dim3(16,16), blk, 0, stream>>>(A, WH+OFF_PQ, WL+OFF_PQ, prevq_b, emb, EN, B);
  // fused dec conv1 + resblock x2 (decoder)
  stack3_k<<<dim3(32,16), blk, 0, stream>>>(
      B, WH+OFF_DW1, WL+OFF_DW1, dec_b1,
      WH+OFF_DR0A, WL+OFF_DR0A, WH+OFF_DR0B, WL+OFF_DR0B,
      WH+OFF_DR1A, WL+OFF_DR1A, WH+OFF_DR1B, WL+OFF_DR1B, A);
  gconv<64,256,4,1, true,true,true, true,false><<<dim3(32,16), blk, 0, stream>>>(
      A, WH+OFF_T1, WL+OFF_T1, dect1_b, nullptr, nullptr, B, 1024, 2048,
      nullptr, 1, 0);
  gconv<32,128,8,1, false,false,true, true,false><<<dim3(64,16), blk, 0, stream>>>(
      B, WH+OFF_T2, WL+OFF_T2, dect2_b, nullptr, nullptr, out, 2048, 4096,
      nullptr, 1, 0);
}

// Round 8
// 517.413 us; speedup vs baseline: 1.3290x; 1.0524x over previous
//
#include <hip/hip_runtime.h>

// ---------------------------------------------------------------------------
// VQ-VAE forward — split-fp16 MFMA everywhere.
// x = h + l*2^-11 (l prescaled by 2^11), w likewise; acc1 = h*wh,
// acc2 = h*wl + l*wh; result = acc1 + acc2/2048.  (fp32-accurate)
// Verified MFMA mapping: A[m=lane&15][k=quad*8+j] (8 consecutive k),
// B rows [n][kk] (8 consecutive kk at col n=lane&15), D col=lane&15,
// row=quad*4+reg.  kk = ci*4 + tap, tap padded to 4 with zero weights.
// R3 lesson: NEVER index register arrays with runtime values.
// R6 lesson: direct-from-global fragment gathers are TA/L1 SEGMENT-bound.
// R7 lesson: global B loads inside the barriered chunk serialize on vmcnt.
// R8 (kept): conv1 stages A AND B through LDS, one barrier/chunk, split-K.
// R9/R10: stack3_k fusion (correct w/ halo zero-masking) — perf-neutral:
// each stack3 ~100us because EVERY k3 stage loads B direct from global at
// col*512B stride = 64 lines/wave-instr, serialized inside barriers (the
// R6/R7 failure mode, x10 per block).
// R11 change: weight layout [col][KP] -> [KP/32][col][32] for ALL KP>32
// weights (c2,c3,er0a,er1a,pq,dw1,dr0a,dr1a,t1,t2). A wave's B-fragment
// request is now ONE contiguous 1KB burst (col*32+quad*8 within a ks
// plane). 1x1 weights already contiguous - unchanged. Pure permutation:
// prep_k decode + load addresses only; numerics identical; conv1 untouched.
// ---------------------------------------------------------------------------

typedef _Float16 half8 __attribute__((ext_vector_type(8)));
typedef float f32x4 __attribute__((ext_vector_type(4)));
union H8u { half8 h; int4 i; };
union P4u { _Float16 e[4]; int2 u; };

__device__ __forceinline__ void splitf(float v, _Float16& h, _Float16& l) {
  h = (_Float16)v; l = (_Float16)((v - (float)h) * 2048.0f);
}
#define INV2048 (1.0f / 2048.0f)

// ---- prepped-weight layout offsets (f16 elements) ----
// KP>32 weights stored [KP/32][NCOL][32]; 1x1 ([NCOL][32]) unchanged.
#define OFF_C1   0        // conv1  [48 kkblk][32 col][64 kkin]
#define OFF_C2   98304    // conv2  [4][64][32]
#define OFF_C3   106496   // conv3  [8][64][32]
#define OFF_ER0A 122880   // enc r0 conv3 [8][32][32]
#define OFF_ER0B 131072   // enc r0 1x1   [64][32]
#define OFF_ER1A 133120
#define OFF_ER1B 141312
#define OFF_PQ   143360   // prevq [2][64][32]
#define OFF_DW1  147456   // dec conv1 [8][64][32]
#define OFF_DR0A 163840
#define OFF_DR0B 172032
#define OFF_DR1A 174080
#define OFF_DR1B 182272
#define OFF_T1   184320   // convT1 [8][64][32] (col=par*32+co)
#define OFF_T2   200704   // convT2 [4][128][32] (col=par*64+co)
#define WTOT     217088

struct WPtrs {
  const float *c1, *c2, *c3, *er0a, *er0b, *er1a, *er1b, *pq,
              *dw1, *dr0a, *dr0b, *dr1a, *dr1b, *t1, *t2;
};

__device__ __forceinline__ int tpose_kt(int par, int tap) {
  if (par == 0) { if (tap == 0) return 3; if (tap == 1) return 1; }
  else          { if (tap == 1) return 2; if (tap == 2) return 0; }
  return -1;
}

__global__ __launch_bounds__(256) void prep_k(WPtrs P, _Float16* __restrict__ WH,
                                              _Float16* __restrict__ WL) {
  int s = blockIdx.x * 256 + threadIdx.x;
  if (s >= WTOT) return;
  float v = 0.f;
  if (s < OFF_C2) {
    // conv1: [kkblk][col][kkin] (k-major blocks for contiguous LDS staging)
    int t = s, kkblk = t >> 11, rem = t & 2047, col = rem >> 6, kkin = rem & 63;
    int kk = kkblk * 64 + kkin;
    v = P.c1[col * 3072 + kk];
  } else if (s < OFF_C3) {
    // conv2 [4][64][32]
    int t = s - OFF_C2;
    int ks = t >> 11, col = (t >> 5) & 63, kkin = t & 31, kk = ks * 32 + kkin;
    v = P.c2[(col * 32 + (kk >> 2)) * 4 + (kk & 3)];
  } else if (s < OFF_ER0A) {
    // c3 [8][64][32]
    int t = s - OFF_C3;
    int ks = t >> 11, col = (t >> 5) & 63, kkin = t & 31, kk = ks * 32 + kkin;
    int tap = kk & 3;
    if (tap < 3) v = P.c3[(col * 64 + (kk >> 2)) * 3 + tap];
  } else if (s < OFF_ER0B) {
    // er0a [8][32][32]
    int t = s - OFF_ER0A;
    int ks = t >> 10, col = (t >> 5) & 31, kkin = t & 31, kk = ks * 32 + kkin;
    int tap = kk & 3;
    if (tap < 3) v = P.er0a[(col * 64 + (kk >> 2)) * 3 + tap];
  } else if (s < OFF_ER1A) {
    int t = s - OFF_ER0B; v = P.er0b[t];          // 1x1 unchanged
  } else if (s < OFF_ER1B) {
    // er1a [8][32][32]
    int t = s - OFF_ER1A;
    int ks = t >> 10, col = (t >> 5) & 31, kkin = t & 31, kk = ks * 32 + kkin;
    int tap = kk & 3;
    if (tap < 3) v = P.er1a[(col * 64 + (kk >> 2)) * 3 + tap];
  } else if (s < OFF_PQ) {
    int t = s - OFF_ER1B; v = P.er1b[t];          // 1x1 unchanged
  } else if (s < OFF_DW1) {
    // prevq [2][64][32]
    int t = s - OFF_PQ;
    int ks = t >> 11, col = (t >> 5) & 63, kkin = t & 31;
    v = P.pq[col * 64 + ks * 32 + kkin];
  } else if (s < OFF_DR0A) {
    // dw1 [8][64][32]
    int t = s - OFF_DW1;
    int ks = t >> 11, col = (t >> 5) & 63, kkin = t & 31, kk = ks * 32 + kkin;
    int tap = kk & 3;
    if (tap < 3) v = P.dw1[(col * 64 + (kk >> 2)) * 3 + tap];
  } else if (s < OFF_DR0B) {
    // dr0a [8][32][32]
    int t = s - OFF_DR0A;
    int ks = t >> 10, col = (t >> 5) & 31, kkin = t & 31, kk = ks * 32 + kkin;
    int tap = kk & 3;
    if (tap < 3) v = P.dr0a[(col * 64 + (kk >> 2)) * 3 + tap];
  } else if (s < OFF_DR1A) {
    int t = s - OFF_DR0B; v = P.dr0b[t];          // 1x1 unchanged
  } else if (s < OFF_DR1B) {
    // dr1a [8][32][32]
    int t = s - OFF_DR1A;
    int ks = t >> 10, col = (t >> 5) & 31, kkin = t & 31, kk = ks * 32 + kkin;
    int tap = kk & 3;
    if (tap < 3) v = P.dr1a[(col * 64 + (kk >> 2)) * 3 + tap];
  } else if (s < OFF_T1) {
    int t = s - OFF_DR1B; v = P.dr1b[t];          // 1x1 unchanged
  } else if (s < OFF_T2) {
    // t1 [8][64][32]
    int t = s - OFF_T1;
    int ks = t >> 11, nn = (t >> 5) & 63, kkin = t & 31, kk = ks * 32 + kkin;
    int par = nn >> 5, co = nn & 31, ci = kk >> 2;
    int kt = tpose_kt(par, kk & 3);
    if (kt >= 0) v = P.t1[(ci * 32 + co) * 4 + kt];
  } else {
    // t2 [4][128][32]
    int t = s - OFF_T2;
    int ks = t >> 12, nn = (t >> 5) & 127, kkin = t & 31, kk = ks * 32 + kkin;
    int par = nn >> 6, co = nn & 63, ci = kk >> 2;
    int kt = tpose_kt(par, kk & 3);
    if (kt >= 0) v = P.t2[(ci * 64 + co) * 4 + kt];
  }
  _Float16 h, l; splitf(v, h, l);
  WH[s] = h; WL[s] = l;
}

// --------------------------- conv1 (768->32, k4 s2) -------------------------
__global__ __launch_bounds__(256, 4) void conv1_k(
    const float* __restrict__ x, const _Float16* __restrict__ WH,
    const _Float16* __restrict__ WL, float* __restrict__ Pout, int cpp) {
  __shared__ _Float16 Hs[2][16 * 136];
  __shared__ _Float16 Ls[2][16 * 136];
  __shared__ _Float16 Bhs[2][32 * 64];
  __shared__ _Float16 Bls[2][32 * 64];
  const int tid = threadIdx.x;
  const int w = tid >> 6, lane = tid & 63, lm = lane & 15, quad = lane >> 4;
  const int m0 = blockIdx.x * 64, n = blockIdx.y, kpart = blockIdx.z;
  const int r = w * 16 + lm;                  // wave-local output row 0..63
  const int pb = 2 * m0 - 1;                  // global pos of local q=0
  const float* xn = x + (size_t)n * 768 * 4096;
  const int r0s = tid / 33, c0s = tid % 33;
  const int r1s = (256 + tid) / 33, c1s = (256 + tid) % 33;
  const int r2s = (512 + tid) / 33, c2s = (512 + tid) % 33;
  const int bcol = tid >> 3, bslot = tid & 7;
  const int bdst = bcol * 64 + ((bslot ^ (bcol & 7)) << 3);

  f32x4 acc1[2], acc2[2];
#pragma unroll
  for (int j = 0; j < 2; ++j)
#pragma unroll
    for (int rr = 0; rr < 4; ++rr) { acc1[j][rr] = 0.f; acc2[j][rr] = 0.f; }

  const int cb0 = kpart * cpp;
  float4 sv0, sv1, sv2;
  H8u bhv, blv;

#define C1_LD1(SV, RS, CS) { \
    int p0 = pb + 4 * (CS); \
    const float* rp = xn + (size_t)(chb + (RS)) * 4096; \
    if (p0 >= 0 && p0 + 3 < 4096) SV = *(const float4*)(rp + p0); \
    else { \
      SV.x = (p0   >= 0 && p0   < 4096) ? rp[p0]   : 0.f; \
      SV.y = (p0+1 >= 0 && p0+1 < 4096) ? rp[p0+1] : 0.f; \
      SV.z = (p0+2 >= 0 && p0+2 < 4096) ? rp[p0+2] : 0.f; \
      SV.w = (p0+3 >= 0 && p0+3 < 4096) ? rp[p0+3] : 0.f; } }

#define C1_LOAD(cc) { \
    int chb = (cb0 + (cc)) * 16; \
    C1_LD1(sv0, r0s, c0s) \
    C1_LD1(sv1, r1s, c1s) \
    if (tid < 16) C1_LD1(sv2, r2s, c2s) \
    bhv.i = *(const int4*)(WH + (size_t)(cb0 + (cc)) * 2048 + tid * 8); \
    blv.i = *(const int4*)(WL + (size_t)(cb0 + (cc)) * 2048 + tid * 8); }

#define C1_WR1(SV, RS, CS, B) { \
    P4u ph, pl; \
    splitf(SV.x, ph.e[0], pl.e[0]); splitf(SV.y, ph.e[1], pl.e[1]); \
    splitf(SV.z, ph.e[2], pl.e[2]); splitf(SV.w, ph.e[3], pl.e[3]); \
    *(int2*)(&Hs[B][(RS) * 136 + 4 * (CS)]) = ph.u; \
    *(int2*)(&Ls[B][(RS) * 136 + 4 * (CS)]) = pl.u; }

#define C1_WRITE(B) { \
    C1_WR1(sv0, r0s, c0s, B) \
    C1_WR1(sv1, r1s, c1s, B) \
    if (tid < 16) C1_WR1(sv2, r2s, c2s, B) \
    *(int4*)(&Bhs[B][bdst]) = bhv.i; \
    *(int4*)(&Bls[B][bdst]) = blv.i; }

#define C1_COMP(B) { \
    const uint* Hdw = (const uint*)(&Hs[B][0]); \
    const uint* Ldw = (const uint*)(&Ls[B][0]); \
    _Pragma("unroll") \
    for (int ks = 0; ks < 2; ++ks) { \
      const int ci0 = ks * 8 + quad * 2; \
      const int bse = ci0 * 68 + r; \
      H8u ah, al; \
      ah.i.x = Hdw[bse];      ah.i.y = Hdw[bse + 1]; \
      ah.i.z = Hdw[bse + 68]; ah.i.w = Hdw[bse + 69]; \
      al.i.x = Ldw[bse];      al.i.y = Ldw[bse + 1]; \
      al.i.z = Ldw[bse + 68]; al.i.w = Ldw[bse + 69]; \
      const int sA = ((4 * ks + quad) ^ (lm & 7)) << 3; \
      H8u b0h, b0l, b1h, b1l; \
      b0h.i = *(const int4*)(&Bhs[B][lm * 64 + sA]); \
      b0l.i = *(const int4*)(&Bls[B][lm * 64 + sA]); \
      b1h.i = *(const int4*)(&Bhs[B][(16 + lm) * 64 + sA]); \
      b1l.i = *(const int4*)(&Bls[B][(16 + lm) * 64 + sA]); \
      acc1[0] = __builtin_amdgcn_mfma_f32_16x16x32_f16(ah.h, b0h.h, acc1[0], 0,0,0); \
      acc2[0] = __builtin_amdgcn_mfma_f32_16x16x32_f16(ah.h, b0l.h, acc2[0], 0,0,0); \
      acc2[0] = __builtin_amdgcn_mfma_f32_16x16x32_f16(al.h, b0h.h, acc2[0], 0,0,0); \
      acc1[1] = __builtin_amdgcn_mfma_f32_16x16x32_f16(ah.h, b1h.h, acc1[1], 0,0,0); \
      acc2[1] = __builtin_amdgcn_mfma_f32_16x16x32_f16(ah.h, b1l.h, acc2[1], 0,0,0); \
      acc2[1] = __builtin_amdgcn_mfma_f32_16x16x32_f16(al.h, b1h.h, acc2[1], 0,0,0); \
    } }

  C1_LOAD(0);
  C1_WRITE(0);
  __syncthreads();
#pragma unroll 1
  for (int cc = 0; cc < cpp; ++cc) {
    const int cur = cc & 1;
    if (cc + 1 < cpp) C1_LOAD(cc + 1);
    C1_COMP(cur);
    if (cc + 1 < cpp) C1_WRITE(cur ^ 1);
    __syncthreads();
  }

#pragma unroll
  for (int j = 0; j < 2; ++j) {
    int col = j * 16 + lm;
    float4 o;
    o.x = acc1[j][0] + acc2[j][0] * INV2048;
    o.y = acc1[j][1] + acc2[j][1] * INV2048;
    o.z = acc1[j][2] + acc2[j][2] * INV2048;
    o.w = acc1[j][3] + acc2[j][3] * INV2048;
    *(float4*)(Pout + (size_t)kpart * (16 * 32 * 2048)
               + ((size_t)n * 32 + col) * 2048 + m0 + w * 16 + quad * 4) = o;
  }
#undef C1_LD1
#undef C1_LOAD
#undef C1_WR1
#undef C1_WRITE
#undef C1_COMP
}

// ---------------- k3 MFMA helper (KP=256, 8 ks, B prefetched) ---------------
// Weights in [8][NCW][32] layout: fragment at (ks*NCW + col)*32 + quad*8.
template<int NTW_, int NCW>
__device__ __forceinline__ void k3_mfma(
    const _Float16* __restrict__ AGH, const _Float16* __restrict__ AGL,
    int arow, const _Float16* __restrict__ WHp, const _Float16* __restrict__ WLp,
    int colb, int lm, int quad, f32x4 (&a1)[NTW_], f32x4 (&a2)[NTW_]) {
  H8u bh[2][NTW_], bl[2][NTW_];
#pragma unroll
  for (int j = 0; j < NTW_; ++j) {
    int col = colb + j * 16 + lm;
    bh[0][j].i = *(const int4*)(WHp + (size_t)col * 32 + quad * 8);
    bl[0][j].i = *(const int4*)(WLp + (size_t)col * 32 + quad * 8);
  }
#pragma unroll
  for (int ks = 0; ks < 8; ++ks) {
    int cur = ks & 1;
    if (ks + 1 < 8) {
#pragma unroll
      for (int j = 0; j < NTW_; ++j) {
        int col = colb + j * 16 + lm;
        bh[cur ^ 1][j].i = *(const int4*)(WHp + (size_t)((ks + 1) * NCW + col) * 32 + quad * 8);
        bl[cur ^ 1][j].i = *(const int4*)(WLp + (size_t)((ks + 1) * NCW + col) * 32 + quad * 8);
      }
    }
    H8u ah, al;
    ah.i = *(const int4*)(&AGH[(arow + lm) * 264 + ks * 32 + quad * 8]);
    al.i = *(const int4*)(&AGL[(arow + lm) * 264 + ks * 32 + quad * 8]);
#pragma unroll
    for (int j = 0; j < NTW_; ++j) {
      a1[j] = __builtin_amdgcn_mfma_f32_16x16x32_f16(ah.h, bh[cur][j].h, a1[j], 0,0,0);
      a2[j] = __builtin_amdgcn_mfma_f32_16x16x32_f16(ah.h, bl[cur][j].h, a2[j], 0,0,0);
      a2[j] = __builtin_amdgcn_mfma_f32_16x16x32_f16(al.h, bh[cur][j].h, a2[j], 0,0,0);
    }
  }
}

// ---------- fused conv(k3,bias) + resblock + resblock (64ch, L=1024) --------
__global__ __launch_bounds__(256, 2) void stack3_k(
    const float* __restrict__ in,
    const _Float16* __restrict__ WAH, const _Float16* __restrict__ WAL,
    const float* __restrict__ biasA,
    const _Float16* __restrict__ W0AH, const _Float16* __restrict__ W0AL,
    const _Float16* __restrict__ W0BH, const _Float16* __restrict__ W0BL,
    const _Float16* __restrict__ W1AH, const _Float16* __restrict__ W1AL,
    const _Float16* __restrict__ W1BH, const _Float16* __restrict__ W1BL,
    float* __restrict__ out) {
  __shared__ float XS[64 * 68];        // x (stride 68) -> reused as s0 (stride 52)
  __shared__ float HP[64 * 68];        // h plane (stride 68, 64 used)
  __shared__ float RP[32 * 52];        // r0a out (48 rows) -> reused r1a out (32)
  __shared__ _Float16 AGH[32 * 264];   // k3 A-gather high; also A2 [48*40]
  __shared__ _Float16 AGL[32 * 264];
  const int tid = threadIdx.x;
  const int w = tid >> 6, lane = tid & 63, lm = lane & 15, quad = lane >> 4;
  const int m0 = blockIdx.x * 32, n = blockIdx.y;
  const float* inN = in + (size_t)n * 64 * 1024;

  // ---- stage x: 68 slots of q, q = p - (m0-17) ----
  {
    const int pb = m0 - 17;
#pragma unroll
    for (int it = 0; it < 5; ++it) {
      int idx = it * 256 + tid;
      if (idx < 64 * 17) {
        int row = idx / 17, c4 = idx % 17;
        int p0 = pb + c4 * 4;
        const float* rp = inN + (size_t)row * 1024;
        float4 v;
        if (p0 >= 0 && p0 + 3 < 1024) v = *(const float4*)(rp + p0);
        else {
          v.x = (p0   >= 0 && p0   < 1024) ? rp[p0]   : 0.f;
          v.y = (p0+1 >= 0 && p0+1 < 1024) ? rp[p0+1] : 0.f;
          v.z = (p0+2 >= 0 && p0+2 < 1024) ? rp[p0+2] : 0.f;
          v.w = (p0+3 >= 0 && p0+3 < 1024) ? rp[p0+3] : 0.f;
        }
        *(float4*)(&XS[row * 68 + c4 * 4]) = v;
      }
    }
  }
  __syncthreads();

#define GATH64(SRC, SSTR, OFS, ROWS, RELUF) { \
    _Pragma("unroll") \
    for (int it = 0; it < (ROWS) / 4; ++it) { \
      int slot = it * 256 + tid; \
      int ci = slot & 63, m = slot >> 6; \
      const float* xr = &SRC[ci * (SSTR) + (OFS) + m]; \
      float a0 = xr[0], a1v = xr[1], a2v = xr[2], a3 = xr[3]; \
      if (RELUF) { a0 = fmaxf(a0,0.f); a1v = fmaxf(a1v,0.f); \
                   a2v = fmaxf(a2v,0.f); a3 = fmaxf(a3,0.f); } \
      P4u ph, pl; \
      splitf(a0, ph.e[0], pl.e[0]); splitf(a1v, ph.e[1], pl.e[1]); \
      splitf(a2v, ph.e[2], pl.e[2]); splitf(a3, ph.e[3], pl.e[3]); \
      *(int2*)(&AGH[m * 264 + ci * 4]) = ph.u; \
      *(int2*)(&AGL[m * 264 + ci * 4]) = pl.u; } }

  // ---- conv A: h on 64 positions, 2 passes of 32 (masked outside [0,1024)) --
#pragma unroll
  for (int P = 0; P < 2; ++P) {
    GATH64(XS, 68, P * 32, 32, false);
    __syncthreads();
    {
      f32x4 a1[2], a2[2];
#pragma unroll
      for (int j = 0; j < 2; ++j)
#pragma unroll
        for (int rr = 0; rr < 4; ++rr) { a1[j][rr] = 0.f; a2[j][rr] = 0.f; }
      k3_mfma<2, 64>(AGH, AGL, (w >> 1) * 16, WAH, WAL, (w & 1) * 32, lm, quad, a1, a2);
#pragma unroll
      for (int j = 0; j < 2; ++j) {
        int col = (w & 1) * 32 + j * 16 + lm;
        float bv = biasA[col];
#pragma unroll
        for (int rr = 0; rr < 4; ++rr) {
          int m = (w >> 1) * 16 + quad * 4 + rr;
          int qh = P * 32 + m;                 // h-plane local index
          int gp = m0 - 16 + qh;               // global position
          float hv = a1[j][rr] + a2[j][rr] * INV2048 + bv;
          HP[col * 68 + qh] = (gp >= 0 && gp < 1024) ? hv : 0.f;
        }
      }
    }
    __syncthreads();
  }

  // ---- r0a: c3(relu h) on 48 positions (pass0: 32 rows, pass1: 16) ----
  GATH64(HP, 68, 7, 32, true);
  __syncthreads();
  {
    f32x4 a1[1], a2[1];
#pragma unroll
    for (int rr = 0; rr < 4; ++rr) { a1[0][rr] = 0.f; a2[0][rr] = 0.f; }
    k3_mfma<1, 32>(AGH, AGL, (w >> 1) * 16, W0AH, W0AL, (w & 1) * 16, lm, quad, a1, a2);
    int col2 = (w & 1) * 16 + lm;
#pragma unroll
    for (int rr = 0; rr < 4; ++rr) {
      int m = (w >> 1) * 16 + quad * 4 + rr;
      RP[col2 * 52 + m] = a1[0][rr] + a2[0][rr] * INV2048;
    }
  }
  __syncthreads();
  GATH64(HP, 68, 39, 16, true);
  __syncthreads();
  if ((w >> 1) == 0) {
    f32x4 a1[1], a2[1];
#pragma unroll
    for (int rr = 0; rr < 4; ++rr) { a1[0][rr] = 0.f; a2[0][rr] = 0.f; }
    k3_mfma<1, 32>(AGH, AGL, 0, W0AH, W0AL, (w & 1) * 16, lm, quad, a1, a2);
    int col2 = (w & 1) * 16 + lm;
#pragma unroll
    for (int rr = 0; rr < 4; ++rr) {
      int m = quad * 4 + rr;
      RP[col2 * 52 + 32 + m] = a1[0][rr] + a2[0][rr] * INV2048;
    }
  }
  __syncthreads();

  // ---- r0b: s0 = h + 1x1(relu r0a) on 48 positions -> XS (stride 52),
  //      masked to 0 outside [0,1024) ----
#pragma unroll
  for (int it = 0; it < 6; ++it) {
    int slot = it * 256 + tid;
    int ci = slot & 31, m = slot >> 5;
    float v = fmaxf(RP[ci * 52 + m], 0.f);
    _Float16 h, l; splitf(v, h, l);
    AGH[m * 40 + ci] = h; AGL[m * 40 + ci] = l;
  }
  __syncthreads();
  {
    int col = w * 16 + lm;
    H8u wbh, wbl;
    wbh.i = *(const int4*)(W0BH + col * 32 + quad * 8);
    wbl.i = *(const int4*)(W0BL + col * 32 + quad * 8);
#pragma unroll
    for (int mt2 = 0; mt2 < 3; ++mt2) {
      f32x4 c1 = {0.f,0.f,0.f,0.f}, c2 = {0.f,0.f,0.f,0.f};
      H8u a2h, a2l;
      a2h.i = *(const int4*)(&AGH[(mt2 * 16 + lm) * 40 + quad * 8]);
      a2l.i = *(const int4*)(&AGL[(mt2 * 16 + lm) * 40 + quad * 8]);
      c1 = __builtin_amdgcn_mfma_f32_16x16x32_f16(a2h.h, wbh.h, c1, 0,0,0);
      c2 = __builtin_amdgcn_mfma_f32_16x16x32_f16(a2h.h, wbl.h, c2, 0,0,0);
      c2 = __builtin_amdgcn_mfma_f32_16x16x32_f16(a2l.h, wbh.h, c2, 0,0,0);
#pragma unroll
      for (int rr = 0; rr < 4; ++rr) {
        int qs = mt2 * 16 + quad * 4 + rr;
        int gp = m0 - 8 + qs;                  // global position of s0 slot
        float sv = HP[col * 68 + qs + 8] + c1[rr] + c2[rr] * INV2048;
        XS[col * 52 + qs] = (gp >= 0 && gp < 1024) ? sv : 0.f;
      }
    }
  }
  __syncthreads();

  // ---- r1a: c3(relu s0) on 32 positions -> RP raw ----
  GATH64(XS, 52, 7, 32, true);
  __syncthreads();
  {
    f32x4 a1[1], a2[1];
#pragma unroll
    for (int rr = 0; rr < 4; ++rr) { a1[0][rr] = 0.f; a2[0][rr] = 0.f; }
    k3_mfma<1, 32>(AGH, AGL, (w >> 1) * 16, W1AH, W1AL, (w & 1) * 16, lm, quad, a1, a2);
    int col2 = (w & 1) * 16 + lm;
#pragma unroll
    for (int rr = 0; rr < 4; ++rr) {
      int m = (w >> 1) * 16 + quad * 4 + rr;
      RP[col2 * 52 + m] = a1[0][rr] + a2[0][rr] * INV2048;
    }
  }
  __syncthreads();

  // ---- r1b: out = s0 + 1x1(relu r1a), store raw ----
#pragma unroll
  for (int it = 0; it < 4; ++it) {
    int slot = it * 256 + tid;
    int ci = slot & 31, m = slot >> 5;
    float v = fmaxf(RP[ci * 52 + m], 0.f);
    _Float16 h, l; splitf(v, h, l);
    AGH[m * 40 + ci] = h; AGL[m * 40 + ci] = l;
  }
  __syncthreads();
  {
    int mt2 = w >> 1, ntb2 = (w & 1) * 2;
    H8u a2h, a2l;
    a2h.i = *(const int4*)(&AGH[(mt2 * 16 + lm) * 40 + quad * 8]);
    a2l.i = *(const int4*)(&AGL[(mt2 * 16 + lm) * 40 + quad * 8]);
#pragma unroll
    for (int j = 0; j < 2; ++j) {
      int col = (ntb2 + j) * 16 + lm;
      H8u wbh, wbl;
      wbh.i = *(const int4*)(W1BH + col * 32 + quad * 8);
      wbl.i = *(const int4*)(W1BL + col * 32 + quad * 8);
      f32x4 c1 = {0.f,0.f,0.f,0.f}, c2 = {0.f,0.f,0.f,0.f};
      c1 = __builtin_amdgcn_mfma_f32_16x16x32_f16(a2h.h, wbh.h, c1, 0,0,0);
      c2 = __builtin_amdgcn_mfma_f32_16x16x32_f16(a2h.h, wbl.h, c2, 0,0,0);
      c2 = __builtin_amdgcn_mfma_f32_16x16x32_f16(a2l.h, wbh.h, c2, 0,0,0);
      float4 o;
#pragma unroll
      for (int rr = 0; rr < 4; ++rr) {
        int m = mt2 * 16 + quad * 4 + rr;
        ((float*)&o)[rr] = XS[col * 52 + m + 8] + c1[rr] + c2[rr] * INV2048;
      }
      *(float4*)(out + ((size_t)n * 64 + col) * 1024 + m0 + mt2 * 16 + quad * 4) = o;
    }
  }
#undef GATH64
}

// ------------------- generic one-shot MFMA conv (M-tile 32) -----------------
template<int CI, int KP, int NT, int STRIDE,
         bool RELU_IN, bool RELU_OUT, bool BIAS, bool TPOSE, bool RESBLK,
         bool PSUM = false>
__global__ __launch_bounds__(256) void gconv(
    const float* __restrict__ in, const _Float16* __restrict__ WH,
    const _Float16* __restrict__ WL, const float* __restrict__ bias,
    const _Float16* __restrict__ W2H, const _Float16* __restrict__ W2L,
    float* __restrict__ out, int Lin, int Lout,
    const float* __restrict__ inbias, int nparts, int pplane) {
  constexpr int CP = 32 * STRIDE + 4;
  constexpr int CP4 = CP / 4;
  constexpr int AP = KP + 8;
  constexpr int KS = KP / 32;
  constexpr int NTW = (NT == 2) ? 1 : NT / 2;
  constexpr int NCW = NT * 16;         // weight columns ([KS][NCW][32] layout)
  __shared__ float xs[CI * CP];
  __shared__ _Float16 Ah[32 * AP];
  __shared__ _Float16 Al[32 * AP];
  __shared__ _Float16 A2h[RESBLK ? 32 * 40 : 1];
  __shared__ _Float16 A2l[RESBLK ? 32 * 40 : 1];
  const int tid = threadIdx.x;
  const int w = tid >> 6, lane = tid & 63, lm = lane & 15, quad = lane >> 4;
  const int mt = w >> 1, ntb = (w & 1) * NTW;
  const int m0 = blockIdx.x * 32, n = blockIdx.y;
  const int base = m0 * STRIDE - 1;
  const float* inN = in + (size_t)n * CI * Lin;
  constexpr int SLOTS = CI * CP4;
#pragma unroll
  for (int it = 0; it < (SLOTS + 255) / 256; ++it) {
    int idx = it * 256 + tid;
    if (idx < SLOTS) {
      int row = idx / CP4, c4 = idx % CP4;
      int p0 = base + c4 * 4;
      const float* rp = inN + (size_t)row * Lin;
      float4 v;
      if (PSUM) {
        v.x = 0.f; v.y = 0.f; v.z = 0.f; v.w = 0.f;
        bool i0 = (p0   >= 0 && p0   < Lin);
        bool i1 = (p0+1 >= 0 && p0+1 < Lin);
        bool i2 = (p0+2 >= 0 && p0+2 < Lin);
        bool i3 = (p0+3 >= 0 && p0+3 < Lin);
        bool full = (p0 >= 0 && p0 + 3 < Lin);
        for (int p = 0; p < nparts; ++p) {
          const float* rpp = rp + (size_t)p * pplane;
          if (full) {
            float4 t = *(const float4*)(rpp + p0);
            v.x += t.x; v.y += t.y; v.z += t.z; v.w += t.w;
          } else {
            if (i0) v.x += rpp[p0];
            if (i1) v.y += rpp[p0+1];
            if (i2) v.z += rpp[p0+2];
            if (i3) v.w += rpp[p0+3];
          }
        }
        float bv = inbias[row];
        v.x = i0 ? fmaxf(v.x + bv, 0.f) : 0.f;
        v.y = i1 ? fmaxf(v.y + bv, 0.f) : 0.f;
        v.z = i2 ? fmaxf(v.z + bv, 0.f) : 0.f;
        v.w = i3 ? fmaxf(v.w + bv, 0.f) : 0.f;
      } else {
        if (p0 >= 0 && p0 + 3 < Lin) v = *(const float4*)(rp + p0);
        else {
          v.x = (p0   >= 0 && p0   < Lin) ? rp[p0]   : 0.f;
          v.y = (p0+1 >= 0 && p0+1 < Lin) ? rp[p0+1] : 0.f;
          v.z = (p0+2 >= 0 && p0+2 < Lin) ? rp[p0+2] : 0.f;
          v.w = (p0+3 >= 0 && p0+3 < Lin) ? rp[p0+3] : 0.f;
        }
      }
      *(float4*)(&xs[row * CP + c4 * 4]) = v;
    }
  }
  __syncthreads();
#pragma unroll
  for (int it = 0; it < (32 * CI) / 256; ++it) {
    int slot = it * 256 + tid;
    int ci = slot & (CI - 1), m = slot / CI;
    const float* xr = &xs[ci * CP + STRIDE * m];
    float a0 = xr[0], a1 = xr[1], a2 = xr[2], a3 = xr[3];
    if (RELU_IN) { a0 = fmaxf(a0,0.f); a1 = fmaxf(a1,0.f);
                   a2 = fmaxf(a2,0.f); a3 = fmaxf(a3,0.f); }
    P4u ph, pl;
    splitf(a0, ph.e[0], pl.e[0]); splitf(a1, ph.e[1], pl.e[1]);
    splitf(a2, ph.e[2], pl.e[2]); splitf(a3, ph.e[3], pl.e[3]);
    *(int2*)(&Ah[m * AP + ci * 4]) = ph.u;
    *(int2*)(&Al[m * AP + ci * 4]) = pl.u;
  }
  __syncthreads();
  f32x4 acc1[NTW], acc2[NTW];
#pragma unroll
  for (int j = 0; j < NTW; ++j)
#pragma unroll
    for (int r = 0; r < 4; ++r) { acc1[j][r] = 0.f; acc2[j][r] = 0.f; }
  H8u bh[2][NTW], bl[2][NTW];
#pragma unroll
  for (int j = 0; j < NTW; ++j) {
    int col = (ntb + j) * 16 + lm;
    bh[0][j].i = *(const int4*)(WH + (size_t)col * 32 + quad * 8);
    bl[0][j].i = *(const int4*)(WL + (size_t)col * 32 + quad * 8);
  }
#pragma unroll
  for (int ks = 0; ks < KS; ++ks) {
    int cur = ks & 1;
    if (ks + 1 < KS) {
#pragma unroll
      for (int j = 0; j < NTW; ++j) {
        int col = (ntb + j) * 16 + lm;
        bh[cur ^ 1][j].i = *(const int4*)(WH + (size_t)((ks + 1) * NCW + col) * 32 + quad * 8);
        bl[cur ^ 1][j].i = *(const int4*)(WL + (size_t)((ks + 1) * NCW + col) * 32 + quad * 8);
      }
    }
    H8u ah, al;
    ah.i = *(const int4*)(&Ah[(mt * 16 + lm) * AP + ks * 32 + quad * 8]);
    al.i = *(const int4*)(&Al[(mt * 16 + lm) * AP + ks * 32 + quad * 8]);
#pragma unroll
    for (int j = 0; j < NTW; ++j) {
      acc1[j] = __builtin_amdgcn_mfma_f32_16x16x32_f16(ah.h, bh[cur][j].h, acc1[j], 0,0,0);
      acc2[j] = __builtin_amdgcn_mfma_f32_16x16x32_f16(ah.h, bl[cur][j].h, acc2[j], 0,0,0);
      acc2[j] = __builtin_amdgcn_mfma_f32_16x16x32_f16(al.h, bh[cur][j].h, acc2[j], 0,0,0);
    }
  }
  if (RESBLK) {
    int co2 = (w & 1) * 16 + lm;
#pragma unroll
    for (int r = 0; r < 4; ++r) {
      float hv = fmaxf(acc1[0][r] + acc2[0][r] * INV2048, 0.f);
      _Float16 hh, hl; splitf(hv, hh, hl);
      int m = mt * 16 + quad * 4 + r;
      A2h[m * 40 + co2] = hh; A2l[m * 40 + co2] = hl;
    }
    __syncthreads();
    f32x4 c1[2], c2[2];
#pragma unroll
    for (int j = 0; j < 2; ++j)
#pragma unroll
      for (int r = 0; r < 4; ++r) { c1[j][r] = 0.f; c2[j][r] = 0.f; }
    H8u a2h, a2l;
    a2h.i = *(const int4*)(&A2h[(mt * 16 + lm) * 40 + quad * 8]);
    a2l.i = *(const int4*)(&A2l[(mt * 16 + lm) * 40 + quad * 8]);
    int ntb2 = (w & 1) * 2;
#pragma unroll
    for (int j = 0; j < 2; ++j) {
      int col = (ntb2 + j) * 16 + lm;
      H8u wbh, wbl;
      wbh.i = *(const int4*)(W2H + col * 32 + quad * 8);
      wbl.i = *(const int4*)(W2L + col * 32 + quad * 8);
      c1[j] = __builtin_amdgcn_mfma_f32_16x16x32_f16(a2h.h, wbh.h, c1[j], 0,0,0);
      c2[j] = __builtin_amdgcn_mfma_f32_16x16x32_f16(a2h.h, wbl.h, c2[j], 0,0,0);
      c2[j] = __builtin_amdgcn_mfma_f32_16x16x32_f16(a2l.h, wbh.h, c2[j], 0,0,0);
    }
#pragma unroll
    for (int j = 0; j < 2; ++j) {
      int col = (ntb2 + j) * 16 + lm;
      float4 o;
#pragma unroll
      for (int r = 0; r < 4; ++r) {
        int m = mt * 16 + quad * 4 + r;
        float res = xs[col * CP + m + 1];
        ((float*)&o)[r] = res + c1[j][r] + c2[j][r] * INV2048;
      }
      *(float4*)(out + ((size_t)n * 64 + col) * Lout + m0 + mt * 16 + quad * 4) = o;
    }
  } else {
    constexpr int CO = TPOSE ? NT * 8 : NT * 16;
#pragma unroll
    for (int j = 0; j < NTW; ++j) {
      int col = (ntb + j) * 16 + lm;
      int par = TPOSE ? (col / CO) : 0;
      int co  = TPOSE ? (col % CO) : col;
      float bv = BIAS ? bias[co] : 0.f;
      float vr[4];
#pragma unroll
      for (int r = 0; r < 4; ++r) {
        float v = acc1[j][r] + acc2[j][r] * INV2048 + bv;
        vr[r] = RELU_OUT ? fmaxf(v, 0.f) : v;
      }
      if (TPOSE) {
#pragma unroll
        for (int r = 0; r < 4; ++r) {
          int m = m0 + mt * 16 + quad * 4 + r;
          out[((size_t)n * CO + co) * Lout + 2 * m + par] = vr[r];
        }
      } else {
        float4 o; o.x = vr[0]; o.y = vr[1]; o.z = vr[2]; o.w = vr[3];
        *(float4*)(out + ((size_t)n * CO + co) * Lout + m0 + mt * 16 + quad * 4) = o;
      }
    }
  }
}

// ------------------------------ codebook norms ------------------------------
__global__ void enorm_k(const float* __restrict__ emb, float* __restrict__ en) {
  int e = blockIdx.x * blockDim.x + threadIdx.x;
  if (e >= 512) return;
  float s = 0.f;
  const float* r = emb + (size_t)e * 64;
  for (int c = 0; c < 64; ++c) s = fmaf(r[c], r[c], s);
  en[e] = s;
}

// ------------------ fused prevq (1x1, relu-in) + VQ -------------------------
__global__ __launch_bounds__(256) void vq_fused(
    const float* __restrict__ sIn, const _Float16* __restrict__ PQH,
    const _Float16* __restrict__ PQL, const float* __restrict__ pqb,
    const float* __restrict__ emb, const float* __restrict__ en,
    float* __restrict__ q) {
  __shared__ float xs[64 * 68];
  __shared__ _Float16 Ah[64 * 72];
  __shared__ _Float16 Al[64 * 72];
  __shared__ float zl[64 * 65];
  __shared__ float dred[4 * 64];
  __shared__ int   ired[4 * 64];
  __shared__ int   idxs[64];
  const int tid = threadIdx.x;
  const int w = tid >> 6, lane = tid & 63, lm = lane & 15, quad = lane >> 4;
  const int n = blockIdx.y, t0 = blockIdx.x * 64;
#pragma unroll
  for (int it = 0; it < 4; ++it) {
    int idx = it * 256 + tid;
    int row = idx >> 4, c4 = idx & 15;
    float4 v = *(const float4*)(sIn + ((size_t)n * 64 + row) * 1024 + t0 + c4 * 4);
    *(float4*)(&xs[row * 68 + c4 * 4]) = v;
  }
  __syncthreads();
#pragma unroll
  for (int it = 0; it < 16; ++it) {
    int slot = it * 256 + tid;
    int ci = slot & 63, t = slot >> 6;
    float v = fmaxf(xs[ci * 68 + t], 0.f);
    _Float16 h, l; splitf(v, h, l);
    Ah[t * 72 + ci] = h; Al[t * 72 + ci] = l;
  }
  __syncthreads();
  f32x4 a1[4], a2[4];
#pragma unroll
  for (int j = 0; j < 4; ++j)
#pragma unroll
    for (int r = 0; r < 4; ++r) { a1[j][r] = 0.f; a2[j][r] = 0.f; }
#pragma unroll
  for (int ks = 0; ks < 2; ++ks) {
    H8u ah, al;
    ah.i = *(const int4*)(&Ah[(w * 16 + lm) * 72 + ks * 32 + quad * 8]);
    al.i = *(const int4*)(&Al[(w * 16 + lm) * 72 + ks * 32 + quad * 8]);
#pragma unroll
    for (int j = 0; j < 4; ++j) {
      int col = j * 16 + lm;
      H8u bh, bl;
      bh.i = *(const int4*)(PQH + (ks * 64 + col) * 32 + quad * 8);
      bl.i = *(const int4*)(PQL + (ks * 64 + col) * 32 + quad * 8);
      a1[j] = __builtin_amdgcn_mfma_f32_16x16x32_f16(ah.h, bh.h, a1[j], 0,0,0);
      a2[j] = __builtin_amdgcn_mfma_f32_16x16x32_f16(ah.h, bl.h, a2[j], 0,0,0);
      a2[j] = __builtin_amdgcn_mfma_f32_16x16x32_f16(al.h, bh.h, a2[j], 0,0,0);
    }
  }
#pragma unroll
  for (int j = 0; j < 4; ++j) {
    int col = j * 16 + lm;
    float bv = pqb[col];
#pragma unroll
    for (int r = 0; r < 4; ++r) {
      int t = w * 16 + quad * 4 + r;
      zl[t * 65 + col] = a1[j][r] + a2[j][r] * INV2048 + bv;
    }
  }
  __syncthreads();
  int tt = tid & 63, cq = tid >> 6;
  float zv[64];
#pragma unroll
  for (int c = 0; c < 64; ++c) zv[c] = zl[tt * 65 + c];
  float best = 1e30f; int bidx = 0;
  for (int e = cq * 128; e < cq * 128 + 128; ++e) {
    const float* er = emb + (size_t)e * 64;
    float dot = 0.f;
#pragma unroll
    for (int c = 0; c < 64; ++c) dot = fmaf(zv[c], er[c], dot);
    float d = en[e] - 2.f * dot;
    if (d < best) { best = d; bidx = e; }
  }
  dred[cq * 64 + tt] = best;
  ired[cq * 64 + tt] = bidx;
  __syncthreads();
  if (cq == 0) {
    for (int j = 1; j < 4; ++j) {
      float d = dred[j * 64 + tt]; int i2 = ired[j * 64 + tt];
      if (d < best || (d == best && i2 < bidx)) { best = d; bidx = i2; }
    }
    idxs[tt] = bidx;
  }
  __syncthreads();
  for (int it = 0; it < 16; ++it) {
    int c = cq * 16 + it;
    q[((size_t)n * 64 + c) * 1024 + t0 + tt] = emb[(size_t)idxs[tt] * 64 + c];
  }
}

// ---------------------------------------------------------------------------
extern "C" void kernel_launch(void* const* d_in, const int* in_sizes, int n_in,
                              void* d_out, int out_size, void* d_ws, size_t ws_size,
                              hipStream_t stream) {
  const float* x        = (const float*)d_in[0];
  const float* enc_b1   = (const float*)d_in[2];
  const float* enc_b2   = (const float*)d_in[4];
  const float* enc_b3   = (const float*)d_in[6];
  const float* prevq_b  = (const float*)d_in[12];
  const float* emb      = (const float*)d_in[13];
  const float* dec_b1   = (const float*)d_in[15];
  const float* dect1_b  = (const float*)d_in[21];
  const float* dect2_b  = (const float*)d_in[23];
  float* out = (float*)d_out;

  WPtrs P;
  P.c1  = (const float*)d_in[1];  P.c2  = (const float*)d_in[3];
  P.c3  = (const float*)d_in[5];  P.er0a = (const float*)d_in[7];
  P.er0b = (const float*)d_in[8]; P.er1a = (const float*)d_in[9];
  P.er1b = (const float*)d_in[10]; P.pq = (const float*)d_in[11];
  P.dw1 = (const float*)d_in[14]; P.dr0a = (const float*)d_in[16];
  P.dr0b = (const float*)d_in[17]; P.dr1a = (const float*)d_in[18];
  P.dr1b = (const float*)d_in[19]; P.t1 = (const float*)d_in[20];
  P.t2  = (const float*)d_in[22];

  float* A  = (float*)d_ws;                   // 1M floats
  float* B  = A + (1u << 20);                 // 1M floats
  float* EN = B + (1u << 20);                 // 512 floats
  _Float16* WH = (_Float16*)(EN + 1024);      // WTOT f16
  _Float16* WL = WH + WTOT;
  float* PP = (float*)(WL + WTOT);            // conv1 split-K partial planes

  const size_t baseBytes = (size_t)((char*)PP - (char*)d_ws);
  const size_t planeB = (size_t)16 * 32 * 2048 * 4;
  int nparts = 1;
  float* Pbuf = A;                            // nparts==1: reuse A directly
  if (ws_size >= baseBytes + 2 * planeB) { nparts = 2; Pbuf = PP; }

  dim3 blk(256);
  prep_k<<<dim3((WTOT + 255) / 256), blk, 0, stream>>>(P, WH, WL);
  enorm_k<<<dim3(2), blk, 0, stream>>>(emb, EN);
  // encoder — conv1 writes raw split-K partials; conv2 sums + bias + relu
  conv1_k<<<dim3(32, 16, nparts), blk, 0, stream>>>(x, WH + OFF_C1, WL + OFF_C1,
                                                    Pbuf, 48 / nparts);
  gconv<32,128,4,2, false,true,true, false,false, true><<<dim3(32,16), blk, 0, stream>>>(
      Pbuf, WH+OFF_C2, WL+OFF_C2, enc_b2, nullptr, nullptr, B, 2048, 1024,
      enc_b1, nparts, 16 * 32 * 2048);
  // fused conv3 + resblock x2 (encoder)
  stack3_k<<<dim3(32,16), blk, 0, stream>>>(
      B, WH+OFF_C3, WL+OFF_C3, enc_b3,
      WH+OFF_ER0A, WL+OFF_ER0A, WH+OFF_ER0B, WL+OFF_ER0B,
      WH+OFF_ER1A, WL+OFF_ER1A, WH+OFF_ER1B, WL+OFF_ER1B, A);
  // VQ (prevq + relu fused)
  vq_fused<<<dim3(16,16), blk, 0, stream>>>(A, WH+OFF_PQ, WL+OFF_PQ, prevq_b, emb, EN, B);
  // fused dec conv1 + resblock x2 (decoder)
  stack3_k<<<dim3(32,16), blk, 0, stream>>>(
      B, WH+OFF_DW1, WL+OFF_DW1, dec_b1,
      WH+OFF_DR0A, WL+OFF_DR0A, WH+OFF_DR0B, WL+OFF_DR0B,
      WH+OFF_DR1A, WL+OFF_DR1A, WH+OFF_DR1B, WL+OFF_DR1B, A);
  gconv<64,256,4,1, true,true,true, true,false><<<dim3(32,16), blk, 0, stream>>>(
      A, WH+OFF_T1, WL+OFF_T1, dect1_b, nullptr, nullptr, B, 1024, 2048,
      nullptr, 1, 0);
  gconv<32,128,8,1, false,false,true, true,false><<<dim3(64,16), blk, 0, stream>>>(
      B, WH+OFF_T2, WL+OFF_T2, dect2_b, nullptr, nullptr, out, 2048, 4096,
      nullptr, 1, 0);
}